// Round 1
// baseline (565.408 us; speedup 1.0000x reference)
//
#include <hip/hip_runtime.h>
#include <math.h>

#define BATCH 4
#define NQ 2048
#define NKEY 2048
#define DMODEL 512
#define NH 8
#define DHEAD 64
#define BH (BATCH * NH)

typedef __attribute__((ext_vector_type(8))) short short8;
typedef __attribute__((ext_vector_type(4))) float f32x4;

#define MFMA16(a, b, c) __builtin_amdgcn_mfma_f32_16x16x32_bf16((a), (b), (c), 0, 0, 0)

// f32 -> bf16 bits, round-to-nearest-even
static __device__ __forceinline__ unsigned short f2b(float f) {
    union { float f; unsigned u; } v; v.f = f;
    unsigned r = (v.u + 0x7fffu + ((v.u >> 16) & 1u)) >> 16;
    return (unsigned short)r;
}

// ---------------------------------------------------------------------------
// Cast both activations f32 -> bf16 (row-major [8192,512])
// ---------------------------------------------------------------------------
__launch_bounds__(256) __global__
void cast_x(const float* __restrict__ a, const float* __restrict__ b,
            unsigned short* __restrict__ da, unsigned short* __restrict__ db) {
    const float* s = blockIdx.y ? b : a;
    unsigned short* d = blockIdx.y ? db : da;
    size_t i = ((size_t)blockIdx.x * 256 + threadIdx.x) * 4;
    float4 v = *(const float4*)(s + i);
    ushort4 o;
    o.x = f2b(v.x); o.y = f2b(v.y); o.z = f2b(v.z); o.w = f2b(v.w);
    *(ushort4*)(d + i) = o;
}

// ---------------------------------------------------------------------------
// Transpose+cast the five 512x512 weights: Wt[n][k] = bf16(W[k][n])
// ---------------------------------------------------------------------------
__launch_bounds__(256) __global__
void trans_w(const float* __restrict__ w0, const float* __restrict__ w1,
             const float* __restrict__ w2, const float* __restrict__ w3,
             const float* __restrict__ w4, unsigned short* __restrict__ dst) {
    const float* src = (blockIdx.z == 0) ? w0 : (blockIdx.z == 1) ? w1 :
                       (blockIdx.z == 2) ? w2 : (blockIdx.z == 3) ? w3 : w4;
    unsigned short* out = dst + (size_t)blockIdx.z * DMODEL * DMODEL;
    __shared__ float t[32][33];
    const int tx = threadIdx.x & 31, ty = threadIdx.x >> 5;  // 32 x 8
    const int k0 = blockIdx.x * 32, n0 = blockIdx.y * 32;
    #pragma unroll
    for (int j = 0; j < 4; ++j)
        t[ty + j * 8][tx] = src[(size_t)(k0 + ty + j * 8) * DMODEL + n0 + tx];
    __syncthreads();
    #pragma unroll
    for (int j = 0; j < 4; ++j)
        out[(size_t)(n0 + ty + j * 8) * DMODEL + k0 + tx] = f2b(t[tx][ty + j * 8]);
}

// ---------------------------------------------------------------------------
// bf16 MFMA GEMM, direct-global fragments (no LDS).  (unchanged this round)
// ---------------------------------------------------------------------------
template <int MODE>
__launch_bounds__(256) __global__
void gemm_bf16(const unsigned short* __restrict__ A,
               const unsigned short* __restrict__ Bt,
               void* __restrict__ Cout, const float* __restrict__ bias,
               const float* __restrict__ resid, int M, int N, int K) {
    const int tid = threadIdx.x;
    const int w = tid >> 6, lane = tid & 63;
    const int l16 = lane & 15, q4 = lane >> 4;
    const int mBase = blockIdx.x * 128 + w * 32;
    const int n0 = blockIdx.y * 64;

    const unsigned short* Arow0 = A + (size_t)(mBase + l16) * K;
    const unsigned short* Arow1 = Arow0 + (size_t)16 * K;
    const unsigned short* Brow0 = Bt + (size_t)(n0 + l16) * K;

    f32x4 z = {0.f, 0.f, 0.f, 0.f};
    f32x4 acc[2][4];
    #pragma unroll
    for (int i = 0; i < 2; ++i)
        #pragma unroll
        for (int t = 0; t < 4; ++t) acc[i][t] = z;

    #pragma unroll 2
    for (int k0 = 0; k0 < K; k0 += 32) {
        const int ko = k0 + q4 * 8;
        short8 a0 = *(const short8*)(Arow0 + ko);
        short8 a1 = *(const short8*)(Arow1 + ko);
        #pragma unroll
        for (int t = 0; t < 4; ++t) {
            short8 b = *(const short8*)(Brow0 + (size_t)t * 16 * K + ko);
            acc[0][t] = MFMA16(a0, b, acc[0][t]);
            acc[1][t] = MFMA16(a1, b, acc[1][t]);
        }
    }

    #pragma unroll
    for (int i = 0; i < 2; ++i) {
        #pragma unroll
        for (int t = 0; t < 4; ++t) {
            #pragma unroll
            for (int r = 0; r < 4; ++r) {
                const int m = mBase + i * 16 + q4 * 4 + r;
                const int n = n0 + t * 16 + l16;
                float v = acc[i][t][r];
                if (MODE == 0) {
                    ((unsigned short*)Cout)[(((size_t)(m >> 11) * NH + (n >> 6)) * NQ + (m & 2047)) * DHEAD + (n & 63)] = f2b(v);
                } else if (MODE == 1) {
                    ((unsigned short*)Cout)[(((size_t)(m >> 11) * NH + (n >> 6)) * DHEAD + (n & 63)) * NKEY + (m & 2047)] = f2b(v);
                } else if (MODE == 2) {
                    ((unsigned short*)Cout)[(size_t)m * N + n] = f2b(resid[(size_t)m * N + n] - (v + bias[n]));
                } else {
                    ((float*)Cout)[(size_t)m * N + n] = v + bias[n];
                }
            }
        }
    }
}

// ---------------------------------------------------------------------------
// Pass 1: colSrcp[bh][k] = 1 / sum_q exp(S[q,k])  (no max subtraction; |S|<~10)
// Wave = 16 k-cols (1 B-frag pair, loaded ONCE); q-loop 32/iter: 4 MFMA + 8 exp.
// Grid: (NKEY/64, BH) = 1024 blocks -> 4096 waves = 16 waves/CU (was 8).
// ---------------------------------------------------------------------------
__launch_bounds__(256) __global__
void attn_pass1(const unsigned short* __restrict__ Qh,
                const unsigned short* __restrict__ Kh,
                float* __restrict__ colSrcp) {
    const int tid = threadIdx.x;
    const int w = tid >> 6, lane = tid & 63;
    const int l16 = lane & 15, q4 = lane >> 4;
    const int bh = blockIdx.y;
    const int kcol0 = blockIdx.x * 64 + w * 16;

    // Persistent B-fragments: 16 k-cols x d=64  (2 short8)
    short8 bk0, bk1;
    {
        const unsigned short* Krow = Kh + ((size_t)bh * NKEY + kcol0 + l16) * DHEAD;
        bk0 = *(const short8*)(Krow + q4 * 8);
        bk1 = *(const short8*)(Krow + 32 + q4 * 8);
    }
    const unsigned short* Qb = Qh + (size_t)bh * NQ * DHEAD;

    f32x4 z = {0.f, 0.f, 0.f, 0.f};
    float csum = 0.f;
    #pragma unroll 2
    for (int q0 = 0; q0 < NQ; q0 += 32) {
        short8 aq[2][2];
        #pragma unroll
        for (int i = 0; i < 2; ++i) {
            const unsigned short* Arow = Qb + (size_t)(q0 + i * 16 + l16) * DHEAD;
            aq[i][0] = *(const short8*)(Arow + q4 * 8);
            aq[i][1] = *(const short8*)(Arow + 32 + q4 * 8);
        }
        #pragma unroll
        for (int i = 0; i < 2; ++i) {
            f32x4 s = MFMA16(aq[i][0], bk0, z);
            s = MFMA16(aq[i][1], bk1, s);
            csum += __expf(s[0]) + __expf(s[1]) + __expf(s[2]) + __expf(s[3]);
        }
    }
    csum += __shfl_xor(csum, 16, 64);
    csum += __shfl_xor(csum, 32, 64);
    if (q4 == 0)
        colSrcp[(size_t)bh * NKEY + kcol0 + l16] = 1.0f / csum;
}

// ---------------------------------------------------------------------------
// Pass 2: E = exp(S)*colSrcp; r_q = sum_k E; O = E @ V; attnb = bf16(O/(1e-12+r_q))
// Wave = 16 q-rows (was 32). k-loop steps 64 = two 32-k sub-tiles with
// double-buffered wave-private E (no __syncthreads).
// Grid: (NQ/64, BH) = 1024 blocks -> 4096 waves = 16 waves/CU (was 8).
// Per sub-tile: 4 QK MFMA, 8 exp, 8 ds_write_u16, 1 ds_read_b128, 4 PV MFMA.
// ---------------------------------------------------------------------------
__launch_bounds__(256) __global__
void attn_pass2(const unsigned short* __restrict__ Qh,
                const unsigned short* __restrict__ Kh,
                const unsigned short* __restrict__ Vt,
                const float* __restrict__ colSrcp,
                unsigned short* __restrict__ attnb) {
    __shared__ unsigned short Elds[4][2][16][40];  // [wave][buf][q][k pad40] = 10 KB
    const int tid = threadIdx.x;
    const int w = tid >> 6, lane = tid & 63;
    const int l16 = lane & 15, q4 = lane >> 4;
    const int bh = blockIdx.y;
    const int b = bh >> 3, h = bh & 7;
    const int q0w = blockIdx.x * 64 + w * 16;

    // Persistent A-fragments: 16 q-rows x d=64
    short8 aq0, aq1;
    {
        const unsigned short* Qrow = Qh + ((size_t)bh * NQ + q0w + l16) * DHEAD;
        aq0 = *(const short8*)(Qrow + q4 * 8);
        aq1 = *(const short8*)(Qrow + 32 + q4 * 8);
    }
    const unsigned short* Kb = Kh + (size_t)bh * NKEY * DHEAD;
    const unsigned short* Vb = Vt + (size_t)bh * DHEAD * NKEY;
    const float* cs = colSrcp + (size_t)bh * NKEY;
    unsigned short* Ew = &Elds[w][0][0][0];

    f32x4 z = {0.f, 0.f, 0.f, 0.f};
    f32x4 o[4];
    #pragma unroll
    for (int t = 0; t < 4; ++t) o[t] = z;
    float rq[4] = {};

    for (int k0 = 0; k0 < NKEY; k0 += 64) {
        // hoisted K-fragments + rcp for BOTH 32-k sub-tiles
        short8 bk[2][2][2];
        float rcp[2][2];
        #pragma unroll
        for (int sub = 0; sub < 2; ++sub) {
            #pragma unroll
            for (int j = 0; j < 2; ++j) {
                const int kc = k0 + sub * 32 + j * 16;
                const unsigned short* Krow = Kb + (size_t)(kc + l16) * DHEAD;
                bk[sub][j][0] = *(const short8*)(Krow + q4 * 8);
                bk[sub][j][1] = *(const short8*)(Krow + 32 + q4 * 8);
                rcp[sub][j] = cs[kc + l16];
            }
        }
        #pragma unroll
        for (int sub = 0; sub < 2; ++sub) {
            const int kb = k0 + sub * 32;
            // V B-fragments (consumed after LDS round-trip: slack)
            short8 bv[4];
            #pragma unroll
            for (int t = 0; t < 4; ++t)
                bv[t] = *(const short8*)(Vb + (size_t)(t * 16 + l16) * NKEY + kb + q4 * 8);
            unsigned short* Eb = Ew + sub * (16 * 40);
            #pragma unroll
            for (int j = 0; j < 2; ++j) {
                f32x4 s = MFMA16(aq0, bk[sub][j][0], z);
                s = MFMA16(aq1, bk[sub][j][1], s);
                #pragma unroll
                for (int r = 0; r < 4; ++r) {
                    float e = __expf(s[r]) * rcp[sub][j];
                    rq[r] += e;
                    Eb[(q4 * 4 + r) * 40 + j * 16 + l16] = f2b(e);
                }
            }
            short8 ea = *(const short8*)(Eb + l16 * 40 + q4 * 8);
            #pragma unroll
            for (int t = 0; t < 4; ++t)
                o[t] = MFMA16(ea, bv[t], o[t]);
        }
    }

    #pragma unroll
    for (int r = 0; r < 4; ++r) {
        float v = rq[r];
        v += __shfl_xor(v, 1, 64);
        v += __shfl_xor(v, 2, 64);
        v += __shfl_xor(v, 4, 64);
        v += __shfl_xor(v, 8, 64);
        rq[r] = 1.0f / (1e-12f + v);
    }
    #pragma unroll
    for (int t = 0; t < 4; ++t)
        #pragma unroll
        for (int r = 0; r < 4; ++r) {
            const int q = q0w + q4 * 4 + r;
            attnb[((size_t)b * NQ + q) * DMODEL + h * DHEAD + t * 16 + l16] =
                f2b(o[t][r] * rq[r]);
        }
}

// ---------------------------------------------------------------------------
extern "C" void kernel_launch(void* const* d_in, const int* in_sizes, int n_in,
                              void* d_out, int out_size, void* d_ws, size_t ws_size,
                              hipStream_t stream) {
    const float* init_query = (const float*)d_in[0];
    const float* embedding  = (const float*)d_in[1];
    const float* Wq = (const float*)d_in[2];
    const float* Wk = (const float*)d_in[3];
    const float* Wv = (const float*)d_in[4];
    const float* W0 = (const float*)d_in[5];
    const float* b0 = (const float*)d_in[6];
    const float* W1 = (const float*)d_in[7];
    const float* b1 = (const float*)d_in[8];
    float* out = (float*)d_out;

    const size_t ACT = (size_t)BATCH * NQ * DMODEL;   // 4M elements
    const size_t WEL = (size_t)DMODEL * DMODEL;       // 256K elements

    unsigned short* Xq   = (unsigned short*)d_ws;          // bf16 init_query
    unsigned short* Xe   = Xq + ACT;                       // bf16 embedding
    unsigned short* Wt   = Xe + ACT;                       // 5 transposed weights
    unsigned short* Qh   = Wt + 5 * WEL;                   // [bh][q][d]
    unsigned short* Kh   = Qh + ACT;                       // [bh][k][d]
    unsigned short* Vtb  = Kh + ACT;                       // [bh][d][k]
    unsigned short* attnb= Vtb + ACT;                      // [8192][512]
    unsigned short* ybuf = attnb + ACT;                    // [8192][512]
    float* colSrcp = (float*)(ybuf + ACT);                 // [bh][k]

    unsigned short* Wqt = Wt + 0 * WEL;
    unsigned short* Wkt = Wt + 1 * WEL;
    unsigned short* Wvt = Wt + 2 * WEL;
    unsigned short* W0t = Wt + 3 * WEL;
    unsigned short* W1t = Wt + 4 * WEL;

    const int M = BATCH * NQ;  // 8192
    dim3 blk(256);
    dim3 gGemm(M / 128, DMODEL / 64);  // 64 x 8

    cast_x<<<dim3(ACT / 1024, 2), blk, 0, stream>>>(init_query, embedding, Xq, Xe);
    trans_w<<<dim3(16, 16, 5), blk, 0, stream>>>(Wq, Wk, Wv, W0, W1, Wt);

    gemm_bf16<0><<<gGemm, blk, 0, stream>>>(Xq, Wqt, Qh, nullptr, nullptr, M, DMODEL, DMODEL);
    gemm_bf16<0><<<gGemm, blk, 0, stream>>>(Xe, Wkt, Kh, nullptr, nullptr, M, DMODEL, DMODEL);
    gemm_bf16<1><<<gGemm, blk, 0, stream>>>(Xe, Wvt, Vtb, nullptr, nullptr, M, DMODEL, DMODEL);

    attn_pass1<<<dim3(NKEY / 64, BH), blk, 0, stream>>>(Qh, Kh, colSrcp);
    attn_pass2<<<dim3(NQ / 64, BH), blk, 0, stream>>>(Qh, Kh, Vtb, colSrcp, attnb);

    gemm_bf16<2><<<gGemm, blk, 0, stream>>>(attnb, W0t, ybuf, b0, init_query, M, DMODEL, DMODEL);
    gemm_bf16<3><<<gGemm, blk, 0, stream>>>(ybuf, W1t, out, b1, nullptr, M, DMODEL, DMODEL);
}

// Round 2
// 327.045 us; speedup vs baseline: 1.7288x; 1.7288x over previous
//
#include <hip/hip_runtime.h>
#include <math.h>

#define BATCH 4
#define NQ 2048
#define NKEY 2048
#define DMODEL 512
#define NH 8
#define DHEAD 64
#define BH (BATCH * NH)

typedef __attribute__((ext_vector_type(8))) short short8;
typedef __attribute__((ext_vector_type(4))) float f32x4;

#define MFMA16(a, b, c) __builtin_amdgcn_mfma_f32_16x16x32_bf16((a), (b), (c), 0, 0, 0)

// f32 -> bf16 bits, round-to-nearest-even
static __device__ __forceinline__ unsigned short f2b(float f) {
    union { float f; unsigned u; } v; v.f = f;
    unsigned r = (v.u + 0x7fffu + ((v.u >> 16) & 1u)) >> 16;
    return (unsigned short)r;
}

// ---------------------------------------------------------------------------
// Cast both activations f32 -> bf16 (row-major [8192,512])
// ---------------------------------------------------------------------------
__launch_bounds__(256) __global__
void cast_x(const float* __restrict__ a, const float* __restrict__ b,
            unsigned short* __restrict__ da, unsigned short* __restrict__ db) {
    const float* s = blockIdx.y ? b : a;
    unsigned short* d = blockIdx.y ? db : da;
    size_t i = ((size_t)blockIdx.x * 256 + threadIdx.x) * 4;
    float4 v = *(const float4*)(s + i);
    ushort4 o;
    o.x = f2b(v.x); o.y = f2b(v.y); o.z = f2b(v.z); o.w = f2b(v.w);
    *(ushort4*)(d + i) = o;
}

// ---------------------------------------------------------------------------
// Transpose+cast the five 512x512 weights: Wt[n][k] = bf16(W[k][n])
// ---------------------------------------------------------------------------
__launch_bounds__(256) __global__
void trans_w(const float* __restrict__ w0, const float* __restrict__ w1,
             const float* __restrict__ w2, const float* __restrict__ w3,
             const float* __restrict__ w4, unsigned short* __restrict__ dst) {
    const float* src = (blockIdx.z == 0) ? w0 : (blockIdx.z == 1) ? w1 :
                       (blockIdx.z == 2) ? w2 : (blockIdx.z == 3) ? w3 : w4;
    unsigned short* out = dst + (size_t)blockIdx.z * DMODEL * DMODEL;
    __shared__ float t[32][33];
    const int tx = threadIdx.x & 31, ty = threadIdx.x >> 5;  // 32 x 8
    const int k0 = blockIdx.x * 32, n0 = blockIdx.y * 32;
    #pragma unroll
    for (int j = 0; j < 4; ++j)
        t[ty + j * 8][tx] = src[(size_t)(k0 + ty + j * 8) * DMODEL + n0 + tx];
    __syncthreads();
    #pragma unroll
    for (int j = 0; j < 4; ++j)
        out[(size_t)(n0 + ty + j * 8) * DMODEL + k0 + tx] = f2b(t[tx][ty + j * 8]);
}

// ---------------------------------------------------------------------------
// bf16 MFMA GEMM, direct-global fragments (no LDS).  (unchanged this round)
// ---------------------------------------------------------------------------
template <int MODE>
__launch_bounds__(256) __global__
void gemm_bf16(const unsigned short* __restrict__ A,
               const unsigned short* __restrict__ Bt,
               void* __restrict__ Cout, const float* __restrict__ bias,
               const float* __restrict__ resid, int M, int N, int K) {
    const int tid = threadIdx.x;
    const int w = tid >> 6, lane = tid & 63;
    const int l16 = lane & 15, q4 = lane >> 4;
    const int mBase = blockIdx.x * 128 + w * 32;
    const int n0 = blockIdx.y * 64;

    const unsigned short* Arow0 = A + (size_t)(mBase + l16) * K;
    const unsigned short* Arow1 = Arow0 + (size_t)16 * K;
    const unsigned short* Brow0 = Bt + (size_t)(n0 + l16) * K;

    f32x4 z = {0.f, 0.f, 0.f, 0.f};
    f32x4 acc[2][4];
    #pragma unroll
    for (int i = 0; i < 2; ++i)
        #pragma unroll
        for (int t = 0; t < 4; ++t) acc[i][t] = z;

    #pragma unroll 2
    for (int k0 = 0; k0 < K; k0 += 32) {
        const int ko = k0 + q4 * 8;
        short8 a0 = *(const short8*)(Arow0 + ko);
        short8 a1 = *(const short8*)(Arow1 + ko);
        #pragma unroll
        for (int t = 0; t < 4; ++t) {
            short8 b = *(const short8*)(Brow0 + (size_t)t * 16 * K + ko);
            acc[0][t] = MFMA16(a0, b, acc[0][t]);
            acc[1][t] = MFMA16(a1, b, acc[1][t]);
        }
    }

    #pragma unroll
    for (int i = 0; i < 2; ++i) {
        #pragma unroll
        for (int t = 0; t < 4; ++t) {
            #pragma unroll
            for (int r = 0; r < 4; ++r) {
                const int m = mBase + i * 16 + q4 * 4 + r;
                const int n = n0 + t * 16 + l16;
                float v = acc[i][t][r];
                if (MODE == 0) {
                    ((unsigned short*)Cout)[(((size_t)(m >> 11) * NH + (n >> 6)) * NQ + (m & 2047)) * DHEAD + (n & 63)] = f2b(v);
                } else if (MODE == 1) {
                    ((unsigned short*)Cout)[(((size_t)(m >> 11) * NH + (n >> 6)) * DHEAD + (n & 63)) * NKEY + (m & 2047)] = f2b(v);
                } else if (MODE == 2) {
                    ((unsigned short*)Cout)[(size_t)m * N + n] = f2b(resid[(size_t)m * N + n] - (v + bias[n]));
                } else {
                    ((float*)Cout)[(size_t)m * N + n] = v + bias[n];
                }
            }
        }
    }
}

// ---------------------------------------------------------------------------
// Pass 1: colSrcp[bh][k] = 1 / sum_q exp(S[q,k])  (no max subtraction; |S|<~10)
// Wave = 16 k-cols persistent in regs. Q-tiles [64 q][64 d] staged to LDS per
// block (coalesced, XOR-swizzled, next-tile regs prefetched under compute).
// Grid: (NKEY/64, BH) = 1024 blocks -> 16 waves/CU.
// ---------------------------------------------------------------------------
__launch_bounds__(256) __global__
void attn_pass1(const unsigned short* __restrict__ Qh,
                const unsigned short* __restrict__ Kh,
                float* __restrict__ colSrcp) {
    __shared__ unsigned short Qt[64 * 64];  // swizzled [q][d], 8 KB
    const int tid = threadIdx.x;
    const int w = tid >> 6, lane = tid & 63;
    const int l16 = lane & 15, q4 = lane >> 4;
    const int bh = blockIdx.y;
    const int kcol0 = blockIdx.x * 64 + w * 16;

    // Persistent B-fragments: 16 k-cols x d=64 (loaded once; uncoalesced but one-time)
    short8 bk0, bk1;
    {
        const unsigned short* Krow = Kh + ((size_t)bh * NKEY + kcol0 + l16) * DHEAD;
        bk0 = *(const short8*)(Krow + q4 * 8);
        bk1 = *(const short8*)(Krow + 32 + q4 * 8);
    }
    const unsigned short* Qb = Qh + (size_t)bh * NQ * DHEAD;
    char* QtB = (char*)Qt;
    const int srow = tid >> 3;            // staging row within 32-row chunk
    const int scolb = (tid & 7) * 16;     // staging byte-col 0..112
    const int rsw = (l16 & 7) << 4;       // read-side swizzle

    f32x4 z = {0.f, 0.f, 0.f, 0.f};
    float csum = 0.f;

    short8 qst[2];
    #pragma unroll
    for (int c = 0; c < 2; ++c)
        qst[c] = *(const short8*)(Qb + (size_t)(c * 32 + srow) * DHEAD + (scolb >> 1));

    for (int q0 = 0; q0 < NQ; q0 += 64) {
        __syncthreads();  // previous tile's reads complete
        #pragma unroll
        for (int c = 0; c < 2; ++c) {
            const int row = c * 32 + srow;
            const int sw = scolb ^ ((row & 7) << 4);
            *(short8*)(QtB + row * 128 + sw) = qst[c];
        }
        if (q0 + 64 < NQ) {  // prefetch next tile into regs (hides under compute)
            #pragma unroll
            for (int c = 0; c < 2; ++c)
                qst[c] = *(const short8*)(Qb + (size_t)(q0 + 64 + c * 32 + srow) * DHEAD + (scolb >> 1));
        }
        __syncthreads();
        #pragma unroll
        for (int qi = 0; qi < 4; ++qi) {
            const int row = qi * 16 + l16;
            short8 a0 = *(const short8*)(QtB + row * 128 + ((q4 * 16) ^ rsw));
            short8 a1 = *(const short8*)(QtB + row * 128 + ((64 + q4 * 16) ^ rsw));
            f32x4 s = MFMA16(a0, bk0, z);
            s = MFMA16(a1, bk1, s);
            csum += __expf(s[0]) + __expf(s[1]) + __expf(s[2]) + __expf(s[3]);
        }
    }
    csum += __shfl_xor(csum, 16, 64);
    csum += __shfl_xor(csum, 32, 64);
    if (q4 == 0)
        colSrcp[(size_t)bh * NKEY + kcol0 + l16] = 1.0f / csum;
}

// ---------------------------------------------------------------------------
// Pass 2: E = exp(S)*colSrcp; r_q = sum_k E; O = E @ V; attnb = bf16(O/(1e-12+r_q))
// Wave = 16 q-rows (persistent Q frags). Per 64-k iteration the BLOCK stages
// K-tile [64k][64d] and V-tile [64d][64k] into swizzled LDS (coalesced,
// next-tile regs prefetched under compute); waves read conflict-free
// ds_read_b128 fragments. Grid: (NQ/64, BH) = 1024 blocks -> 16 waves/CU.
// ---------------------------------------------------------------------------
__launch_bounds__(256) __global__
void attn_pass2(const unsigned short* __restrict__ Qh,
                const unsigned short* __restrict__ Kh,
                const unsigned short* __restrict__ Vt,
                const float* __restrict__ colSrcp,
                unsigned short* __restrict__ attnb) {
    __shared__ unsigned short Kt[64 * 64];         // swizzled [k][d], 8 KB
    __shared__ unsigned short Vtile[64 * 64];      // swizzled [d][k], 8 KB
    __shared__ unsigned short Elds[4][2][16][40];  // [wave][buf][q][k pad40] = 10 KB
    const int tid = threadIdx.x;
    const int w = tid >> 6, lane = tid & 63;
    const int l16 = lane & 15, q4 = lane >> 4;
    const int bh = blockIdx.y;
    const int b = bh >> 3, h = bh & 7;
    const int q0w = blockIdx.x * 64 + w * 16;

    // Persistent A-fragments: 16 q-rows x d=64 (one-time load)
    short8 aq0, aq1;
    {
        const unsigned short* Qrow = Qh + ((size_t)bh * NQ + q0w + l16) * DHEAD;
        aq0 = *(const short8*)(Qrow + q4 * 8);
        aq1 = *(const short8*)(Qrow + 32 + q4 * 8);
    }
    const unsigned short* Kb = Kh + (size_t)bh * NKEY * DHEAD;
    const unsigned short* Vb = Vt + (size_t)bh * DHEAD * NKEY;
    const float* cs = colSrcp + (size_t)bh * NKEY;
    unsigned short* Ew = &Elds[w][0][0][0];
    char* KtB = (char*)Kt;
    char* VtB = (char*)Vtile;

    const int srow = tid >> 3;            // 0..31
    const int scolb = (tid & 7) * 16;     // 0..112
    const int rsw = (l16 & 7) << 4;

    f32x4 z = {0.f, 0.f, 0.f, 0.f};
    f32x4 o[4];
    #pragma unroll
    for (int t = 0; t < 4; ++t) o[t] = z;
    float rq[4] = {};

    // prologue: stage regs for k0 = 0
    short8 kst[2], vst[2];
    #pragma unroll
    for (int c = 0; c < 2; ++c) {
        const int row = c * 32 + srow;
        kst[c] = *(const short8*)(Kb + (size_t)row * DHEAD + (scolb >> 1));
        vst[c] = *(const short8*)(Vb + (size_t)row * NKEY + (scolb >> 1));
    }

    for (int k0 = 0; k0 < NKEY; k0 += 64) {
        __syncthreads();  // previous tile's fragment reads complete
        #pragma unroll
        for (int c = 0; c < 2; ++c) {
            const int row = c * 32 + srow;
            const int sw = scolb ^ ((row & 7) << 4);
            *(short8*)(KtB + row * 128 + sw) = kst[c];
            *(short8*)(VtB + row * 128 + sw) = vst[c];
        }
        if (k0 + 64 < NKEY) {  // prefetch next tile into regs
            #pragma unroll
            for (int c = 0; c < 2; ++c) {
                const int row = c * 32 + srow;
                kst[c] = *(const short8*)(Kb + (size_t)(k0 + 64 + row) * DHEAD + (scolb >> 1));
                vst[c] = *(const short8*)(Vb + (size_t)row * NKEY + (k0 + 64) + (scolb >> 1));
            }
        }
        // hoist rcp for both sub-tiles (1-line loads, hidden under compute)
        float rcp[2][2];
        #pragma unroll
        for (int sub = 0; sub < 2; ++sub)
            #pragma unroll
            for (int j = 0; j < 2; ++j)
                rcp[sub][j] = cs[k0 + sub * 32 + j * 16 + l16];
        __syncthreads();

        #pragma unroll
        for (int sub = 0; sub < 2; ++sub) {
            // K fragments from LDS (conflict-free swizzled b128)
            short8 bk[2][2];
            #pragma unroll
            for (int j = 0; j < 2; ++j) {
                const int row = sub * 32 + j * 16 + l16;
                bk[j][0] = *(const short8*)(KtB + row * 128 + ((q4 * 16) ^ rsw));
                bk[j][1] = *(const short8*)(KtB + row * 128 + ((64 + q4 * 16) ^ rsw));
            }
            // V fragments from LDS
            short8 bv[4];
            #pragma unroll
            for (int t = 0; t < 4; ++t) {
                const int row = t * 16 + l16;  // d-row
                bv[t] = *(const short8*)(VtB + row * 128 + ((sub * 64 + q4 * 16) ^ rsw));
            }
            unsigned short* Eb = Ew + sub * (16 * 40);
            #pragma unroll
            for (int j = 0; j < 2; ++j) {
                f32x4 s = MFMA16(aq0, bk[j][0], z);
                s = MFMA16(aq1, bk[j][1], s);
                #pragma unroll
                for (int r = 0; r < 4; ++r) {
                    float e = __expf(s[r]) * rcp[sub][j];
                    rq[r] += e;
                    Eb[(q4 * 4 + r) * 40 + j * 16 + l16] = f2b(e);
                }
            }
            short8 ea = *(const short8*)(Eb + l16 * 40 + q4 * 8);
            #pragma unroll
            for (int t = 0; t < 4; ++t)
                o[t] = MFMA16(ea, bv[t], o[t]);
        }
    }

    #pragma unroll
    for (int r = 0; r < 4; ++r) {
        float v = rq[r];
        v += __shfl_xor(v, 1, 64);
        v += __shfl_xor(v, 2, 64);
        v += __shfl_xor(v, 4, 64);
        v += __shfl_xor(v, 8, 64);
        rq[r] = 1.0f / (1e-12f + v);
    }
    #pragma unroll
    for (int t = 0; t < 4; ++t)
        #pragma unroll
        for (int r = 0; r < 4; ++r) {
            const int q = q0w + q4 * 4 + r;
            attnb[((size_t)b * NQ + q) * DMODEL + h * DHEAD + t * 16 + l16] =
                f2b(o[t][r] * rq[r]);
        }
}

// ---------------------------------------------------------------------------
extern "C" void kernel_launch(void* const* d_in, const int* in_sizes, int n_in,
                              void* d_out, int out_size, void* d_ws, size_t ws_size,
                              hipStream_t stream) {
    const float* init_query = (const float*)d_in[0];
    const float* embedding  = (const float*)d_in[1];
    const float* Wq = (const float*)d_in[2];
    const float* Wk = (const float*)d_in[3];
    const float* Wv = (const float*)d_in[4];
    const float* W0 = (const float*)d_in[5];
    const float* b0 = (const float*)d_in[6];
    const float* W1 = (const float*)d_in[7];
    const float* b1 = (const float*)d_in[8];
    float* out = (float*)d_out;

    const size_t ACT = (size_t)BATCH * NQ * DMODEL;   // 4M elements
    const size_t WEL = (size_t)DMODEL * DMODEL;       // 256K elements

    unsigned short* Xq   = (unsigned short*)d_ws;          // bf16 init_query
    unsigned short* Xe   = Xq + ACT;                       // bf16 embedding
    unsigned short* Wt   = Xe + ACT;                       // 5 transposed weights
    unsigned short* Qh   = Wt + 5 * WEL;                   // [bh][q][d]
    unsigned short* Kh   = Qh + ACT;                       // [bh][k][d]
    unsigned short* Vtb  = Kh + ACT;                       // [bh][d][k]
    unsigned short* attnb= Vtb + ACT;                      // [8192][512]
    unsigned short* ybuf = attnb + ACT;                    // [8192][512]
    float* colSrcp = (float*)(ybuf + ACT);                 // [bh][k]

    unsigned short* Wqt = Wt + 0 * WEL;
    unsigned short* Wkt = Wt + 1 * WEL;
    unsigned short* Wvt = Wt + 2 * WEL;
    unsigned short* W0t = Wt + 3 * WEL;
    unsigned short* W1t = Wt + 4 * WEL;

    const int M = BATCH * NQ;  // 8192
    dim3 blk(256);
    dim3 gGemm(M / 128, DMODEL / 64);  // 64 x 8

    cast_x<<<dim3(ACT / 1024, 2), blk, 0, stream>>>(init_query, embedding, Xq, Xe);
    trans_w<<<dim3(16, 16, 5), blk, 0, stream>>>(Wq, Wk, Wv, W0, W1, Wt);

    gemm_bf16<0><<<gGemm, blk, 0, stream>>>(Xq, Wqt, Qh, nullptr, nullptr, M, DMODEL, DMODEL);
    gemm_bf16<0><<<gGemm, blk, 0, stream>>>(Xe, Wkt, Kh, nullptr, nullptr, M, DMODEL, DMODEL);
    gemm_bf16<1><<<gGemm, blk, 0, stream>>>(Xe, Wvt, Vtb, nullptr, nullptr, M, DMODEL, DMODEL);

    attn_pass1<<<dim3(NKEY / 64, BH), blk, 0, stream>>>(Qh, Kh, colSrcp);
    attn_pass2<<<dim3(NQ / 64, BH), blk, 0, stream>>>(Qh, Kh, Vtb, colSrcp, attnb);

    gemm_bf16<2><<<gGemm, blk, 0, stream>>>(attnb, W0t, ybuf, b0, init_query, M, DMODEL, DMODEL);
    gemm_bf16<3><<<gGemm, blk, 0, stream>>>(ybuf, W1t, out, b1, nullptr, M, DMODEL, DMODEL);
}

// Round 3
// 244.632 us; speedup vs baseline: 2.3113x; 1.3369x over previous
//
#include <hip/hip_runtime.h>
#include <math.h>

#define BATCH 4
#define NQ 2048
#define NKEY 2048
#define DMODEL 512
#define NH 8
#define DHEAD 64
#define BH (BATCH * NH)

typedef __attribute__((ext_vector_type(8))) short short8;
typedef __attribute__((ext_vector_type(4))) float f32x4;

#define MFMA16(a, b, c) __builtin_amdgcn_mfma_f32_16x16x32_bf16((a), (b), (c), 0, 0, 0)

// f32 -> bf16 bits, round-to-nearest-even
static __device__ __forceinline__ unsigned short f2b(float f) {
    union { float f; unsigned u; } v; v.f = f;
    unsigned r = (v.u + 0x7fffu + ((v.u >> 16) & 1u)) >> 16;
    return (unsigned short)r;
}

// ---------------------------------------------------------------------------
// Cast both activations f32 -> bf16 (row-major [8192,512])
// ---------------------------------------------------------------------------
__launch_bounds__(256) __global__
void cast_x(const float* __restrict__ a, const float* __restrict__ b,
            unsigned short* __restrict__ da, unsigned short* __restrict__ db) {
    const float* s = blockIdx.y ? b : a;
    unsigned short* d = blockIdx.y ? db : da;
    size_t i = ((size_t)blockIdx.x * 256 + threadIdx.x) * 4;
    float4 v = *(const float4*)(s + i);
    ushort4 o;
    o.x = f2b(v.x); o.y = f2b(v.y); o.z = f2b(v.z); o.w = f2b(v.w);
    *(ushort4*)(d + i) = o;
}

// ---------------------------------------------------------------------------
// Transpose+cast the five 512x512 weights: Wt[n][k] = bf16(W[k][n])
// ---------------------------------------------------------------------------
__launch_bounds__(256) __global__
void trans_w(const float* __restrict__ w0, const float* __restrict__ w1,
             const float* __restrict__ w2, const float* __restrict__ w3,
             const float* __restrict__ w4, unsigned short* __restrict__ dst) {
    const float* src = (blockIdx.z == 0) ? w0 : (blockIdx.z == 1) ? w1 :
                       (blockIdx.z == 2) ? w2 : (blockIdx.z == 3) ? w3 : w4;
    unsigned short* out = dst + (size_t)blockIdx.z * DMODEL * DMODEL;
    __shared__ float t[32][33];
    const int tx = threadIdx.x & 31, ty = threadIdx.x >> 5;  // 32 x 8
    const int k0 = blockIdx.x * 32, n0 = blockIdx.y * 32;
    #pragma unroll
    for (int j = 0; j < 4; ++j)
        t[ty + j * 8][tx] = src[(size_t)(k0 + ty + j * 8) * DMODEL + n0 + tx];
    __syncthreads();
    #pragma unroll
    for (int j = 0; j < 4; ++j)
        out[(size_t)(n0 + ty + j * 8) * DMODEL + k0 + tx] = f2b(t[tx][ty + j * 8]);
}

// ---------------------------------------------------------------------------
// LDS-staged GEMM core: BM=128, BN=64, BK=64, 256 thr / 4 waves.
// A [M,K] bf16 row-major; Bt [N,K] bf16. Coalesced reg-prefetch staging into
// XOR-swizzled LDS; conflict-free ds_read_b128 fragments. MFMA accumulation
// order identical to the direct-global version (k ascending, 32/step).
// ---------------------------------------------------------------------------
__device__ __forceinline__
void gemm_core(const unsigned short* __restrict__ A0,   // = A + mTile*K
               const unsigned short* __restrict__ B0,   // = Bt + n0*K
               int K, int tid, unsigned short* Al, unsigned short* Bl,
               f32x4 acc[2][4]) {
    const int w = tid >> 6, lane = tid & 63;
    const int l16 = lane & 15, q4 = lane >> 4;
    char* AlB = (char*)Al;
    char* BlB = (char*)Bl;
    const int srow = tid >> 3;           // 0..31
    const int scolb = (tid & 7) * 16;    // byte col 0..112
    const int skoff = (tid & 7) * 8;     // k-element offset

    f32x4 z = {0.f, 0.f, 0.f, 0.f};
    #pragma unroll
    for (int i = 0; i < 2; ++i)
        #pragma unroll
        for (int t = 0; t < 4; ++t) acc[i][t] = z;

    // prologue: stage regs for k0 = 0
    short8 ast[4], bst[2];
    #pragma unroll
    for (int c = 0; c < 4; ++c)
        ast[c] = *(const short8*)(A0 + (size_t)(c * 32 + srow) * K + skoff);
    #pragma unroll
    for (int c = 0; c < 2; ++c)
        bst[c] = *(const short8*)(B0 + (size_t)(c * 32 + srow) * K + skoff);

    for (int k0 = 0; k0 < K; k0 += 64) {
        __syncthreads();  // previous tile's fragment reads complete
        #pragma unroll
        for (int c = 0; c < 4; ++c) {
            const int row = c * 32 + srow;
            *(short8*)(AlB + row * 128 + (scolb ^ ((row & 7) << 4))) = ast[c];
        }
        #pragma unroll
        for (int c = 0; c < 2; ++c) {
            const int row = c * 32 + srow;
            *(short8*)(BlB + row * 128 + (scolb ^ ((row & 7) << 4))) = bst[c];
        }
        if (k0 + 64 < K) {  // prefetch next K-tile into regs (hides under compute)
            #pragma unroll
            for (int c = 0; c < 4; ++c)
                ast[c] = *(const short8*)(A0 + (size_t)(c * 32 + srow) * K + k0 + 64 + skoff);
            #pragma unroll
            for (int c = 0; c < 2; ++c)
                bst[c] = *(const short8*)(B0 + (size_t)(c * 32 + srow) * K + k0 + 64 + skoff);
        }
        __syncthreads();

        #pragma unroll
        for (int kk = 0; kk < 2; ++kk) {
            const int kb = kk * 64;  // byte base within 128B row
            const int rswA0 = ((w * 32 + l16) & 7) << 4;
            short8 a0 = *(const short8*)(AlB + (w * 32 + l16) * 128 + ((kb + q4 * 16) ^ rswA0));
            short8 a1 = *(const short8*)(AlB + (w * 32 + 16 + l16) * 128 + ((kb + q4 * 16) ^ rswA0));
            short8 bfr[4];
            #pragma unroll
            for (int t = 0; t < 4; ++t) {
                const int row = t * 16 + l16;
                bfr[t] = *(const short8*)(BlB + row * 128 + ((kb + q4 * 16) ^ ((row & 7) << 4)));
            }
            #pragma unroll
            for (int t = 0; t < 4; ++t) {
                acc[0][t] = MFMA16(a0, bfr[t], acc[0][t]);
                acc[1][t] = MFMA16(a1, bfr[t], acc[1][t]);
            }
        }
    }
}

// ---------------------------------------------------------------------------
// Fused QKV projection: grid.z selects {Q, K, V}.
// z=0: Xq@Wq -> head-split Qh   z=1: Xe@Wk -> head-split Kh
// z=2: Xe@Wv -> transposed Vt[((b*8+h)*64+d)*2048+s]  (ushort4 stores)
// ---------------------------------------------------------------------------
__launch_bounds__(256) __global__
void gemm_qkv(const unsigned short* __restrict__ Xq,
              const unsigned short* __restrict__ Xe,
              const unsigned short* __restrict__ Wt,
              unsigned short* __restrict__ Qh,
              unsigned short* __restrict__ Kh,
              unsigned short* __restrict__ Vtb) {
    __shared__ unsigned short Al[128 * 64];  // 16KB
    __shared__ unsigned short Bl[64 * 64];   // 8KB
    const int tid = threadIdx.x;
    const int zsel = blockIdx.z;
    const int K = DMODEL;
    const unsigned short* A = (zsel == 0) ? Xq : Xe;
    const unsigned short* B0 = Wt + (size_t)zsel * DMODEL * DMODEL + (size_t)(blockIdx.y * 64) * K;
    const unsigned short* A0 = A + (size_t)(blockIdx.x * 128) * K;

    f32x4 acc[2][4];
    gemm_core(A0, B0, K, tid, Al, Bl, acc);

    const int w = tid >> 6, lane = tid & 63;
    const int l16 = lane & 15, q4 = lane >> 4;
    const int mBase = blockIdx.x * 128 + w * 32;
    const int n0 = blockIdx.y * 64;

    if (zsel < 2) {
        unsigned short* out = (zsel == 0) ? Qh : Kh;
        #pragma unroll
        for (int i = 0; i < 2; ++i)
            #pragma unroll
            for (int t = 0; t < 4; ++t)
                #pragma unroll
                for (int r = 0; r < 4; ++r) {
                    const int m = mBase + i * 16 + q4 * 4 + r;
                    const int n = n0 + t * 16 + l16;
                    out[(((size_t)(m >> 11) * NH + (n >> 6)) * NQ + (m & 2047)) * DHEAD + (n & 63)] = f2b(acc[i][t][r]);
                }
    } else {
        #pragma unroll
        for (int i = 0; i < 2; ++i)
            #pragma unroll
            for (int t = 0; t < 4; ++t) {
                const int m0 = mBase + i * 16 + q4 * 4;  // 4-aligned
                const int n = n0 + t * 16 + l16;
                ushort4 p;
                p.x = f2b(acc[i][t][0]); p.y = f2b(acc[i][t][1]);
                p.z = f2b(acc[i][t][2]); p.w = f2b(acc[i][t][3]);
                *(ushort4*)(Vtb + (((size_t)(m0 >> 11) * NH + (n >> 6)) * DHEAD + (n & 63)) * NKEY + (m0 & 2047)) = p;
            }
    }
}

// ---------------------------------------------------------------------------
// LDS-staged GEMM, modes 2/3:
// MODE 2: bf16 store  C[m*N+n] = bf16(resid - (acc + bias[n]))
// MODE 3: f32 store   C[m*N+n] = acc + bias[n]
// ---------------------------------------------------------------------------
template <int MODE>
__launch_bounds__(256) __global__
void gemm_bf16(const unsigned short* __restrict__ A,
               const unsigned short* __restrict__ Bt,
               void* __restrict__ Cout, const float* __restrict__ bias,
               const float* __restrict__ resid, int M, int N, int K) {
    __shared__ unsigned short Al[128 * 64];
    __shared__ unsigned short Bl[64 * 64];
    const int tid = threadIdx.x;
    const unsigned short* A0 = A + (size_t)(blockIdx.x * 128) * K;
    const unsigned short* B0 = Bt + (size_t)(blockIdx.y * 64) * K;

    f32x4 acc[2][4];
    gemm_core(A0, B0, K, tid, Al, Bl, acc);

    const int w = tid >> 6, lane = tid & 63;
    const int l16 = lane & 15, q4 = lane >> 4;
    const int mBase = blockIdx.x * 128 + w * 32;
    const int n0 = blockIdx.y * 64;

    #pragma unroll
    for (int i = 0; i < 2; ++i)
        #pragma unroll
        for (int t = 0; t < 4; ++t)
            #pragma unroll
            for (int r = 0; r < 4; ++r) {
                const int m = mBase + i * 16 + q4 * 4 + r;
                const int n = n0 + t * 16 + l16;
                float v = acc[i][t][r];
                if (MODE == 2) {
                    ((unsigned short*)Cout)[(size_t)m * N + n] = f2b(resid[(size_t)m * N + n] - (v + bias[n]));
                } else {
                    ((float*)Cout)[(size_t)m * N + n] = v + bias[n];
                }
            }
}

// ---------------------------------------------------------------------------
// Pass 1: colSrcp[bh][k] = 1 / sum_q exp(S[q,k])  (no max subtraction; |S|<~10)
// Wave = 16 k-cols persistent in regs. Q-tiles [64 q][64 d] staged to LDS per
// block (coalesced, XOR-swizzled, next-tile regs prefetched under compute).
// ---------------------------------------------------------------------------
__launch_bounds__(256) __global__
void attn_pass1(const unsigned short* __restrict__ Qh,
                const unsigned short* __restrict__ Kh,
                float* __restrict__ colSrcp) {
    __shared__ unsigned short Qt[64 * 64];  // swizzled [q][d], 8 KB
    const int tid = threadIdx.x;
    const int w = tid >> 6, lane = tid & 63;
    const int l16 = lane & 15, q4 = lane >> 4;
    const int bh = blockIdx.y;
    const int kcol0 = blockIdx.x * 64 + w * 16;

    short8 bk0, bk1;
    {
        const unsigned short* Krow = Kh + ((size_t)bh * NKEY + kcol0 + l16) * DHEAD;
        bk0 = *(const short8*)(Krow + q4 * 8);
        bk1 = *(const short8*)(Krow + 32 + q4 * 8);
    }
    const unsigned short* Qb = Qh + (size_t)bh * NQ * DHEAD;
    char* QtB = (char*)Qt;
    const int srow = tid >> 3;
    const int scolb = (tid & 7) * 16;
    const int rsw = (l16 & 7) << 4;

    f32x4 z = {0.f, 0.f, 0.f, 0.f};
    float csum = 0.f;

    short8 qst[2];
    #pragma unroll
    for (int c = 0; c < 2; ++c)
        qst[c] = *(const short8*)(Qb + (size_t)(c * 32 + srow) * DHEAD + (scolb >> 1));

    for (int q0 = 0; q0 < NQ; q0 += 64) {
        __syncthreads();
        #pragma unroll
        for (int c = 0; c < 2; ++c) {
            const int row = c * 32 + srow;
            const int sw = scolb ^ ((row & 7) << 4);
            *(short8*)(QtB + row * 128 + sw) = qst[c];
        }
        if (q0 + 64 < NQ) {
            #pragma unroll
            for (int c = 0; c < 2; ++c)
                qst[c] = *(const short8*)(Qb + (size_t)(q0 + 64 + c * 32 + srow) * DHEAD + (scolb >> 1));
        }
        __syncthreads();
        #pragma unroll
        for (int qi = 0; qi < 4; ++qi) {
            const int row = qi * 16 + l16;
            short8 a0 = *(const short8*)(QtB + row * 128 + ((q4 * 16) ^ rsw));
            short8 a1 = *(const short8*)(QtB + row * 128 + ((64 + q4 * 16) ^ rsw));
            f32x4 s = MFMA16(a0, bk0, z);
            s = MFMA16(a1, bk1, s);
            csum += __expf(s[0]) + __expf(s[1]) + __expf(s[2]) + __expf(s[3]);
        }
    }
    csum += __shfl_xor(csum, 16, 64);
    csum += __shfl_xor(csum, 32, 64);
    if (q4 == 0)
        colSrcp[(size_t)bh * NKEY + kcol0 + l16] = 1.0f / csum;
}

// ---------------------------------------------------------------------------
// Pass 2: E = exp(S)*colSrcp; r_q = sum_k E; O = E @ V; attnb = bf16(O/(1e-12+r_q))
// Wave = 16 q-rows (persistent Q frags). Per 64-k iter the block stages K/V
// tiles into swizzled LDS (coalesced, reg-prefetched).
// ---------------------------------------------------------------------------
__launch_bounds__(256) __global__
void attn_pass2(const unsigned short* __restrict__ Qh,
                const unsigned short* __restrict__ Kh,
                const unsigned short* __restrict__ Vt,
                const float* __restrict__ colSrcp,
                unsigned short* __restrict__ attnb) {
    __shared__ unsigned short Kt[64 * 64];
    __shared__ unsigned short Vtile[64 * 64];
    __shared__ unsigned short Elds[4][2][16][40];
    const int tid = threadIdx.x;
    const int w = tid >> 6, lane = tid & 63;
    const int l16 = lane & 15, q4 = lane >> 4;
    const int bh = blockIdx.y;
    const int b = bh >> 3, h = bh & 7;
    const int q0w = blockIdx.x * 64 + w * 16;

    short8 aq0, aq1;
    {
        const unsigned short* Qrow = Qh + ((size_t)bh * NQ + q0w + l16) * DHEAD;
        aq0 = *(const short8*)(Qrow + q4 * 8);
        aq1 = *(const short8*)(Qrow + 32 + q4 * 8);
    }
    const unsigned short* Kb = Kh + (size_t)bh * NKEY * DHEAD;
    const unsigned short* Vb = Vt + (size_t)bh * DHEAD * NKEY;
    const float* cs = colSrcp + (size_t)bh * NKEY;
    unsigned short* Ew = &Elds[w][0][0][0];
    char* KtB = (char*)Kt;
    char* VtB = (char*)Vtile;

    const int srow = tid >> 3;
    const int scolb = (tid & 7) * 16;
    const int rsw = (l16 & 7) << 4;

    f32x4 z = {0.f, 0.f, 0.f, 0.f};
    f32x4 o[4];
    #pragma unroll
    for (int t = 0; t < 4; ++t) o[t] = z;
    float rq[4] = {};

    short8 kst[2], vst[2];
    #pragma unroll
    for (int c = 0; c < 2; ++c) {
        const int row = c * 32 + srow;
        kst[c] = *(const short8*)(Kb + (size_t)row * DHEAD + (scolb >> 1));
        vst[c] = *(const short8*)(Vb + (size_t)row * NKEY + (scolb >> 1));
    }

    for (int k0 = 0; k0 < NKEY; k0 += 64) {
        __syncthreads();
        #pragma unroll
        for (int c = 0; c < 2; ++c) {
            const int row = c * 32 + srow;
            const int sw = scolb ^ ((row & 7) << 4);
            *(short8*)(KtB + row * 128 + sw) = kst[c];
            *(short8*)(VtB + row * 128 + sw) = vst[c];
        }
        if (k0 + 64 < NKEY) {
            #pragma unroll
            for (int c = 0; c < 2; ++c) {
                const int row = c * 32 + srow;
                kst[c] = *(const short8*)(Kb + (size_t)(k0 + 64 + row) * DHEAD + (scolb >> 1));
                vst[c] = *(const short8*)(Vb + (size_t)row * NKEY + (k0 + 64) + (scolb >> 1));
            }
        }
        float rcp[2][2];
        #pragma unroll
        for (int sub = 0; sub < 2; ++sub)
            #pragma unroll
            for (int j = 0; j < 2; ++j)
                rcp[sub][j] = cs[k0 + sub * 32 + j * 16 + l16];
        __syncthreads();

        #pragma unroll
        for (int sub = 0; sub < 2; ++sub) {
            short8 bk[2][2];
            #pragma unroll
            for (int j = 0; j < 2; ++j) {
                const int row = sub * 32 + j * 16 + l16;
                bk[j][0] = *(const short8*)(KtB + row * 128 + ((q4 * 16) ^ rsw));
                bk[j][1] = *(const short8*)(KtB + row * 128 + ((64 + q4 * 16) ^ rsw));
            }
            short8 bv[4];
            #pragma unroll
            for (int t = 0; t < 4; ++t) {
                const int row = t * 16 + l16;
                bv[t] = *(const short8*)(VtB + row * 128 + ((sub * 64 + q4 * 16) ^ rsw));
            }
            unsigned short* Eb = Ew + sub * (16 * 40);
            #pragma unroll
            for (int j = 0; j < 2; ++j) {
                f32x4 s = MFMA16(aq0, bk[j][0], z);
                s = MFMA16(aq1, bk[j][1], s);
                #pragma unroll
                for (int r = 0; r < 4; ++r) {
                    float e = __expf(s[r]) * rcp[sub][j];
                    rq[r] += e;
                    Eb[(q4 * 4 + r) * 40 + j * 16 + l16] = f2b(e);
                }
            }
            short8 ea = *(const short8*)(Eb + l16 * 40 + q4 * 8);
            #pragma unroll
            for (int t = 0; t < 4; ++t)
                o[t] = MFMA16(ea, bv[t], o[t]);
        }
    }

    #pragma unroll
    for (int r = 0; r < 4; ++r) {
        float v = rq[r];
        v += __shfl_xor(v, 1, 64);
        v += __shfl_xor(v, 2, 64);
        v += __shfl_xor(v, 4, 64);
        v += __shfl_xor(v, 8, 64);
        rq[r] = 1.0f / (1e-12f + v);
    }
    #pragma unroll
    for (int t = 0; t < 4; ++t)
        #pragma unroll
        for (int r = 0; r < 4; ++r) {
            const int q = q0w + q4 * 4 + r;
            attnb[((size_t)b * NQ + q) * DMODEL + h * DHEAD + t * 16 + l16] =
                f2b(o[t][r] * rq[r]);
        }
}

// ---------------------------------------------------------------------------
extern "C" void kernel_launch(void* const* d_in, const int* in_sizes, int n_in,
                              void* d_out, int out_size, void* d_ws, size_t ws_size,
                              hipStream_t stream) {
    const float* init_query = (const float*)d_in[0];
    const float* embedding  = (const float*)d_in[1];
    const float* Wq = (const float*)d_in[2];
    const float* Wk = (const float*)d_in[3];
    const float* Wv = (const float*)d_in[4];
    const float* W0 = (const float*)d_in[5];
    const float* b0 = (const float*)d_in[6];
    const float* W1 = (const float*)d_in[7];
    const float* b1 = (const float*)d_in[8];
    float* out = (float*)d_out;

    const size_t ACT = (size_t)BATCH * NQ * DMODEL;   // 4M elements
    const size_t WEL = (size_t)DMODEL * DMODEL;       // 256K elements

    unsigned short* Xq   = (unsigned short*)d_ws;          // bf16 init_query
    unsigned short* Xe   = Xq + ACT;                       // bf16 embedding
    unsigned short* Wt   = Xe + ACT;                       // 5 transposed weights
    unsigned short* Qh   = Wt + 5 * WEL;                   // [bh][q][d]
    unsigned short* Kh   = Qh + ACT;                       // [bh][k][d]
    unsigned short* Vtb  = Kh + ACT;                       // [bh][d][k]
    unsigned short* attnb= Vtb + ACT;                      // [8192][512]
    unsigned short* ybuf = attnb + ACT;                    // [8192][512]
    float* colSrcp = (float*)(ybuf + ACT);                 // [bh][k]

    unsigned short* W0t = Wt + 3 * WEL;
    unsigned short* W1t = Wt + 4 * WEL;

    const int M = BATCH * NQ;  // 8192
    dim3 blk(256);
    dim3 gGemm(M / 128, DMODEL / 64);  // 64 x 8

    cast_x<<<dim3(ACT / 1024, 2), blk, 0, stream>>>(init_query, embedding, Xq, Xe);
    trans_w<<<dim3(16, 16, 5), blk, 0, stream>>>(Wq, Wk, Wv, W0, W1, Wt);

    gemm_qkv<<<dim3(M / 128, DMODEL / 64, 3), blk, 0, stream>>>(Xq, Xe, Wt, Qh, Kh, Vtb);

    attn_pass1<<<dim3(NKEY / 64, BH), blk, 0, stream>>>(Qh, Kh, colSrcp);
    attn_pass2<<<dim3(NQ / 64, BH), blk, 0, stream>>>(Qh, Kh, Vtb, colSrcp, attnb);

    gemm_bf16<2><<<gGemm, blk, 0, stream>>>(attnb, W0t, ybuf, b0, init_query, M, DMODEL, DMODEL);
    gemm_bf16<3><<<gGemm, blk, 0, stream>>>(ybuf, W1t, out, b1, nullptr, M, DMODEL, DMODEL);
}

// Round 4
// 227.132 us; speedup vs baseline: 2.4893x; 1.0770x over previous
//
#include <hip/hip_runtime.h>
#include <math.h>

#define BATCH 4
#define NQ 2048
#define NKEY 2048
#define DMODEL 512
#define NH 8
#define DHEAD 64
#define BH (BATCH * NH)

typedef __attribute__((ext_vector_type(8))) short short8;
typedef __attribute__((ext_vector_type(4))) float f32x4;

#define MFMA16(a, b, c) __builtin_amdgcn_mfma_f32_16x16x32_bf16((a), (b), (c), 0, 0, 0)

// f32 -> bf16 bits, round-to-nearest-even
static __device__ __forceinline__ unsigned short f2b(float f) {
    union { float f; unsigned u; } v; v.f = f;
    unsigned r = (v.u + 0x7fffu + ((v.u >> 16) & 1u)) >> 16;
    return (unsigned short)r;
}

// ---------------------------------------------------------------------------
// Cast both activations f32 -> bf16 (row-major [8192,512])
// ---------------------------------------------------------------------------
__launch_bounds__(256) __global__
void cast_x(const float* __restrict__ a, const float* __restrict__ b,
            unsigned short* __restrict__ da, unsigned short* __restrict__ db) {
    const float* s = blockIdx.y ? b : a;
    unsigned short* d = blockIdx.y ? db : da;
    size_t i = ((size_t)blockIdx.x * 256 + threadIdx.x) * 4;
    float4 v = *(const float4*)(s + i);
    ushort4 o;
    o.x = f2b(v.x); o.y = f2b(v.y); o.z = f2b(v.z); o.w = f2b(v.w);
    *(ushort4*)(d + i) = o;
}

// ---------------------------------------------------------------------------
// Transpose+cast the five 512x512 weights: Wt[n][k] = bf16(W[k][n])
// ---------------------------------------------------------------------------
__launch_bounds__(256) __global__
void trans_w(const float* __restrict__ w0, const float* __restrict__ w1,
             const float* __restrict__ w2, const float* __restrict__ w3,
             const float* __restrict__ w4, unsigned short* __restrict__ dst) {
    const float* src = (blockIdx.z == 0) ? w0 : (blockIdx.z == 1) ? w1 :
                       (blockIdx.z == 2) ? w2 : (blockIdx.z == 3) ? w3 : w4;
    unsigned short* out = dst + (size_t)blockIdx.z * DMODEL * DMODEL;
    __shared__ float t[32][33];
    const int tx = threadIdx.x & 31, ty = threadIdx.x >> 5;  // 32 x 8
    const int k0 = blockIdx.x * 32, n0 = blockIdx.y * 32;
    #pragma unroll
    for (int j = 0; j < 4; ++j)
        t[ty + j * 8][tx] = src[(size_t)(k0 + ty + j * 8) * DMODEL + n0 + tx];
    __syncthreads();
    #pragma unroll
    for (int j = 0; j < 4; ++j)
        out[(size_t)(n0 + ty + j * 8) * DMODEL + k0 + tx] = f2b(t[tx][ty + j * 8]);
}

// ---------------------------------------------------------------------------
// LDS-staged GEMM core: BM=128, BN=64, BK=64, 256 thr / 4 waves. (unchanged)
// ---------------------------------------------------------------------------
__device__ __forceinline__
void gemm_core(const unsigned short* __restrict__ A0,   // = A + mTile*K
               const unsigned short* __restrict__ B0,   // = Bt + n0*K
               int K, int tid, unsigned short* Al, unsigned short* Bl,
               f32x4 acc[2][4]) {
    const int w = tid >> 6, lane = tid & 63;
    const int l16 = lane & 15, q4 = lane >> 4;
    char* AlB = (char*)Al;
    char* BlB = (char*)Bl;
    const int srow = tid >> 3;           // 0..31
    const int scolb = (tid & 7) * 16;    // byte col 0..112
    const int skoff = (tid & 7) * 8;     // k-element offset

    f32x4 z = {0.f, 0.f, 0.f, 0.f};
    #pragma unroll
    for (int i = 0; i < 2; ++i)
        #pragma unroll
        for (int t = 0; t < 4; ++t) acc[i][t] = z;

    // prologue: stage regs for k0 = 0
    short8 ast[4], bst[2];
    #pragma unroll
    for (int c = 0; c < 4; ++c)
        ast[c] = *(const short8*)(A0 + (size_t)(c * 32 + srow) * K + skoff);
    #pragma unroll
    for (int c = 0; c < 2; ++c)
        bst[c] = *(const short8*)(B0 + (size_t)(c * 32 + srow) * K + skoff);

    for (int k0 = 0; k0 < K; k0 += 64) {
        __syncthreads();  // previous tile's fragment reads complete
        #pragma unroll
        for (int c = 0; c < 4; ++c) {
            const int row = c * 32 + srow;
            *(short8*)(AlB + row * 128 + (scolb ^ ((row & 7) << 4))) = ast[c];
        }
        #pragma unroll
        for (int c = 0; c < 2; ++c) {
            const int row = c * 32 + srow;
            *(short8*)(BlB + row * 128 + (scolb ^ ((row & 7) << 4))) = bst[c];
        }
        if (k0 + 64 < K) {  // prefetch next K-tile into regs (hides under compute)
            #pragma unroll
            for (int c = 0; c < 4; ++c)
                ast[c] = *(const short8*)(A0 + (size_t)(c * 32 + srow) * K + k0 + 64 + skoff);
            #pragma unroll
            for (int c = 0; c < 2; ++c)
                bst[c] = *(const short8*)(B0 + (size_t)(c * 32 + srow) * K + k0 + 64 + skoff);
        }
        __syncthreads();

        #pragma unroll
        for (int kk = 0; kk < 2; ++kk) {
            const int kb = kk * 64;  // byte base within 128B row
            const int rswA0 = ((w * 32 + l16) & 7) << 4;
            short8 a0 = *(const short8*)(AlB + (w * 32 + l16) * 128 + ((kb + q4 * 16) ^ rswA0));
            short8 a1 = *(const short8*)(AlB + (w * 32 + 16 + l16) * 128 + ((kb + q4 * 16) ^ rswA0));
            short8 bfr[4];
            #pragma unroll
            for (int t = 0; t < 4; ++t) {
                const int row = t * 16 + l16;
                bfr[t] = *(const short8*)(BlB + row * 128 + ((kb + q4 * 16) ^ ((row & 7) << 4)));
            }
            #pragma unroll
            for (int t = 0; t < 4; ++t) {
                acc[0][t] = MFMA16(a0, bfr[t], acc[0][t]);
                acc[1][t] = MFMA16(a1, bfr[t], acc[1][t]);
            }
        }
    }
}

// ---------------------------------------------------------------------------
// Fused QKV projection: grid.z selects {Q, K, V}.  (unchanged)
// ---------------------------------------------------------------------------
__launch_bounds__(256) __global__
void gemm_qkv(const unsigned short* __restrict__ Xq,
              const unsigned short* __restrict__ Xe,
              const unsigned short* __restrict__ Wt,
              unsigned short* __restrict__ Qh,
              unsigned short* __restrict__ Kh,
              unsigned short* __restrict__ Vtb) {
    __shared__ unsigned short Al[128 * 64];  // 16KB
    __shared__ unsigned short Bl[64 * 64];   // 8KB
    const int tid = threadIdx.x;
    const int zsel = blockIdx.z;
    const int K = DMODEL;
    const unsigned short* A = (zsel == 0) ? Xq : Xe;
    const unsigned short* B0 = Wt + (size_t)zsel * DMODEL * DMODEL + (size_t)(blockIdx.y * 64) * K;
    const unsigned short* A0 = A + (size_t)(blockIdx.x * 128) * K;

    f32x4 acc[2][4];
    gemm_core(A0, B0, K, tid, Al, Bl, acc);

    const int w = tid >> 6, lane = tid & 63;
    const int l16 = lane & 15, q4 = lane >> 4;
    const int mBase = blockIdx.x * 128 + w * 32;
    const int n0 = blockIdx.y * 64;

    if (zsel < 2) {
        unsigned short* out = (zsel == 0) ? Qh : Kh;
        #pragma unroll
        for (int i = 0; i < 2; ++i)
            #pragma unroll
            for (int t = 0; t < 4; ++t)
                #pragma unroll
                for (int r = 0; r < 4; ++r) {
                    const int m = mBase + i * 16 + q4 * 4 + r;
                    const int n = n0 + t * 16 + l16;
                    out[(((size_t)(m >> 11) * NH + (n >> 6)) * NQ + (m & 2047)) * DHEAD + (n & 63)] = f2b(acc[i][t][r]);
                }
    } else {
        #pragma unroll
        for (int i = 0; i < 2; ++i)
            #pragma unroll
            for (int t = 0; t < 4; ++t) {
                const int m0 = mBase + i * 16 + q4 * 4;  // 4-aligned
                const int n = n0 + t * 16 + l16;
                ushort4 p;
                p.x = f2b(acc[i][t][0]); p.y = f2b(acc[i][t][1]);
                p.z = f2b(acc[i][t][2]); p.w = f2b(acc[i][t][3]);
                *(ushort4*)(Vtb + (((size_t)(m0 >> 11) * NH + (n >> 6)) * DHEAD + (n & 63)) * NKEY + (m0 & 2047)) = p;
            }
    }
}

// ---------------------------------------------------------------------------
// LDS-staged GEMM, modes 2/3.  (unchanged)
// ---------------------------------------------------------------------------
template <int MODE>
__launch_bounds__(256) __global__
void gemm_bf16(const unsigned short* __restrict__ A,
               const unsigned short* __restrict__ Bt,
               void* __restrict__ Cout, const float* __restrict__ bias,
               const float* __restrict__ resid, int M, int N, int K) {
    __shared__ unsigned short Al[128 * 64];
    __shared__ unsigned short Bl[64 * 64];
    const int tid = threadIdx.x;
    const unsigned short* A0 = A + (size_t)(blockIdx.x * 128) * K;
    const unsigned short* B0 = Bt + (size_t)(blockIdx.y * 64) * K;

    f32x4 acc[2][4];
    gemm_core(A0, B0, K, tid, Al, Bl, acc);

    const int w = tid >> 6, lane = tid & 63;
    const int l16 = lane & 15, q4 = lane >> 4;
    const int mBase = blockIdx.x * 128 + w * 32;
    const int n0 = blockIdx.y * 64;

    #pragma unroll
    for (int i = 0; i < 2; ++i)
        #pragma unroll
        for (int t = 0; t < 4; ++t)
            #pragma unroll
            for (int r = 0; r < 4; ++r) {
                const int m = mBase + i * 16 + q4 * 4 + r;
                const int n = n0 + t * 16 + l16;
                float v = acc[i][t][r];
                if (MODE == 2) {
                    ((unsigned short*)Cout)[(size_t)m * N + n] = f2b(resid[(size_t)m * N + n] - (v + bias[n]));
                } else {
                    ((float*)Cout)[(size_t)m * N + n] = v + bias[n];
                }
            }
}

// ---------------------------------------------------------------------------
// Pass 1: colSrcp[bh][k] = 1 / sum_q exp(S[q,k])  (no max subtraction; |S|<~10)
// 512 thr / 8 waves; wave = 16 k-cols persistent in regs; block = 128 k-cols.
// Q-tiles [64q][64d] DOUBLE-BUFFERED in swizzled LDS; ONE barrier per iter
// (stage-write of tile i+1 overlaps compute of tile i).
// Grid: (NKEY/128, BH) = 512 blocks -> 2 blocks/CU, 16 waves/CU, no tail.
// ---------------------------------------------------------------------------
__launch_bounds__(512) __global__
void attn_pass1(const unsigned short* __restrict__ Qh,
                const unsigned short* __restrict__ Kh,
                float* __restrict__ colSrcp) {
    __shared__ unsigned short Qt[2][64 * 64];  // 2 x 8 KB, swizzled [q][d]
    const int tid = threadIdx.x;
    const int w = tid >> 6, lane = tid & 63;
    const int l16 = lane & 15, q4 = lane >> 4;
    const int bh = blockIdx.y;
    const int kcol0 = blockIdx.x * 128 + w * 16;

    short8 bk0, bk1;
    {
        const unsigned short* Krow = Kh + ((size_t)bh * NKEY + kcol0 + l16) * DHEAD;
        bk0 = *(const short8*)(Krow + q4 * 8);
        bk1 = *(const short8*)(Krow + 32 + q4 * 8);
    }
    const unsigned short* Qb = Qh + (size_t)bh * NQ * DHEAD;
    const int srow = tid >> 3;            // 0..63 (one row-chunk per thread)
    const int skoff = (tid & 7) * 8;      // k-element offset within row
    const int ssw = ((tid & 7) * 16) ^ ((srow & 7) << 4);
    const int rsw = (l16 & 7) << 4;

    f32x4 z = {0.f, 0.f, 0.f, 0.f};
    float csum = 0.f;

    // prologue: tile0 -> buf0; tile1 into regs
    short8 qst = *(const short8*)(Qb + (size_t)srow * DHEAD + skoff);
    *(short8*)((char*)Qt[0] + srow * 128 + ssw) = qst;
    qst = *(const short8*)(Qb + (size_t)(64 + srow) * DHEAD + skoff);
    __syncthreads();

    for (int it = 0; it < 32; ++it) {
        const int q0 = it * 64;
        char* QtB = (char*)Qt[it & 1];
        char* QtN = (char*)Qt[(it & 1) ^ 1];

        // stage tile it+1 into the idle buffer; prefetch tile it+2
        if (it < 31) {
            *(short8*)(QtN + srow * 128 + ssw) = qst;
            if (it < 30)
                qst = *(const short8*)(Qb + (size_t)(q0 + 128 + srow) * DHEAD + skoff);
        }

        #pragma unroll
        for (int qi = 0; qi < 4; ++qi) {
            const int row = qi * 16 + l16;
            short8 a0 = *(const short8*)(QtB + row * 128 + ((q4 * 16) ^ rsw));
            short8 a1 = *(const short8*)(QtB + row * 128 + ((64 + q4 * 16) ^ rsw));
            f32x4 s = MFMA16(a0, bk0, z);
            s = MFMA16(a1, bk1, s);
            csum += __expf(s[0]) + __expf(s[1]) + __expf(s[2]) + __expf(s[3]);
        }
        __syncthreads();
    }
    csum += __shfl_xor(csum, 16, 64);
    csum += __shfl_xor(csum, 32, 64);
    if (q4 == 0)
        colSrcp[(size_t)bh * NKEY + kcol0 + l16] = 1.0f / csum;
}

// ---------------------------------------------------------------------------
// Pass 2: E = exp(S)*colSrcp; r_q = sum_k E; O = E @ V; attnb = bf16(O/(1e-12+r_q))
// 512 thr / 8 waves; wave = 16 q-rows (persistent Q frags); block = 128 q-rows.
// K/V tiles [64][64] DOUBLE-BUFFERED in swizzled LDS; ONE barrier per 64-key
// iteration; stage-write + global prefetch overlap compute. Inner per-sub body
// (QK MFMA -> exp -> E LDS round-trip -> PV MFMA) bit-identical to round 3.
// Grid: (NQ/128, BH) = 512 blocks -> 2 blocks/CU, 16 waves/CU, no tail.
// ---------------------------------------------------------------------------
__launch_bounds__(512) __global__
void attn_pass2(const unsigned short* __restrict__ Qh,
                const unsigned short* __restrict__ Kh,
                const unsigned short* __restrict__ Vt,
                const float* __restrict__ colSrcp,
                unsigned short* __restrict__ attnb) {
    __shared__ unsigned short Kt[2][64 * 64];      // 16 KB
    __shared__ unsigned short Vtile[2][64 * 64];   // 16 KB
    __shared__ unsigned short Elds[8][2][16][40];  // 20 KB
    const int tid = threadIdx.x;
    const int w = tid >> 6, lane = tid & 63;
    const int l16 = lane & 15, q4 = lane >> 4;
    const int bh = blockIdx.y;
    const int b = bh >> 3, h = bh & 7;
    const int q0w = blockIdx.x * 128 + w * 16;

    short8 aq0, aq1;
    {
        const unsigned short* Qrow = Qh + ((size_t)bh * NQ + q0w + l16) * DHEAD;
        aq0 = *(const short8*)(Qrow + q4 * 8);
        aq1 = *(const short8*)(Qrow + 32 + q4 * 8);
    }
    const unsigned short* Kb = Kh + (size_t)bh * NKEY * DHEAD;
    const unsigned short* Vb = Vt + (size_t)bh * DHEAD * NKEY;
    const float* cs = colSrcp + (size_t)bh * NKEY;
    unsigned short* Ew = &Elds[w][0][0][0];

    const int srow = tid >> 3;            // 0..63
    const int skoff = (tid & 7) * 8;
    const int ssw = ((tid & 7) * 16) ^ ((srow & 7) << 4);
    const int rsw = (l16 & 7) << 4;

    f32x4 z = {0.f, 0.f, 0.f, 0.f};
    f32x4 o[4];
    #pragma unroll
    for (int t = 0; t < 4; ++t) o[t] = z;
    float rq[4] = {};

    // prologue: tile0 -> buf0; tile1 into regs
    short8 kst = *(const short8*)(Kb + (size_t)srow * DHEAD + skoff);
    short8 vst = *(const short8*)(Vb + (size_t)srow * NKEY + skoff);
    *(short8*)((char*)Kt[0] + srow * 128 + ssw) = kst;
    *(short8*)((char*)Vtile[0] + srow * 128 + ssw) = vst;
    kst = *(const short8*)(Kb + (size_t)(64 + srow) * DHEAD + skoff);
    vst = *(const short8*)(Vb + (size_t)srow * NKEY + 64 + skoff);
    __syncthreads();

    for (int it = 0; it < 32; ++it) {
        const int k0 = it * 64;
        char* KtB = (char*)Kt[it & 1];
        char* VtB = (char*)Vtile[it & 1];
        char* KtN = (char*)Kt[(it & 1) ^ 1];
        char* VtN = (char*)Vtile[(it & 1) ^ 1];

        float rcp[2][2];
        #pragma unroll
        for (int sub = 0; sub < 2; ++sub)
            #pragma unroll
            for (int j = 0; j < 2; ++j)
                rcp[sub][j] = cs[k0 + sub * 32 + j * 16 + l16];

        // stage tile it+1 into idle buffers; prefetch tile it+2 into regs
        if (it < 31) {
            *(short8*)(KtN + srow * 128 + ssw) = kst;
            *(short8*)(VtN + srow * 128 + ssw) = vst;
            if (it < 30) {
                kst = *(const short8*)(Kb + (size_t)(k0 + 128 + srow) * DHEAD + skoff);
                vst = *(const short8*)(Vb + (size_t)srow * NKEY + (k0 + 128) + skoff);
            }
        }

        #pragma unroll
        for (int sub = 0; sub < 2; ++sub) {
            short8 bk[2][2];
            #pragma unroll
            for (int j = 0; j < 2; ++j) {
                const int row = sub * 32 + j * 16 + l16;
                bk[j][0] = *(const short8*)(KtB + row * 128 + ((q4 * 16) ^ rsw));
                bk[j][1] = *(const short8*)(KtB + row * 128 + ((64 + q4 * 16) ^ rsw));
            }
            short8 bv[4];
            #pragma unroll
            for (int t = 0; t < 4; ++t) {
                const int row = t * 16 + l16;
                bv[t] = *(const short8*)(VtB + row * 128 + ((sub * 64 + q4 * 16) ^ rsw));
            }
            unsigned short* Eb = Ew + sub * (16 * 40);
            #pragma unroll
            for (int j = 0; j < 2; ++j) {
                f32x4 s = MFMA16(aq0, bk[j][0], z);
                s = MFMA16(aq1, bk[j][1], s);
                #pragma unroll
                for (int r = 0; r < 4; ++r) {
                    float e = __expf(s[r]) * rcp[sub][j];
                    rq[r] += e;
                    Eb[(q4 * 4 + r) * 40 + j * 16 + l16] = f2b(e);
                }
            }
            short8 ea = *(const short8*)(Eb + l16 * 40 + q4 * 8);
            #pragma unroll
            for (int t = 0; t < 4; ++t)
                o[t] = MFMA16(ea, bv[t], o[t]);
        }
        __syncthreads();
    }

    #pragma unroll
    for (int r = 0; r < 4; ++r) {
        float v = rq[r];
        v += __shfl_xor(v, 1, 64);
        v += __shfl_xor(v, 2, 64);
        v += __shfl_xor(v, 4, 64);
        v += __shfl_xor(v, 8, 64);
        rq[r] = 1.0f / (1e-12f + v);
    }
    #pragma unroll
    for (int t = 0; t < 4; ++t)
        #pragma unroll
        for (int r = 0; r < 4; ++r) {
            const int q = q0w + q4 * 4 + r;
            attnb[((size_t)b * NQ + q) * DMODEL + h * DHEAD + t * 16 + l16] =
                f2b(o[t][r] * rq[r]);
        }
}

// ---------------------------------------------------------------------------
extern "C" void kernel_launch(void* const* d_in, const int* in_sizes, int n_in,
                              void* d_out, int out_size, void* d_ws, size_t ws_size,
                              hipStream_t stream) {
    const float* init_query = (const float*)d_in[0];
    const float* embedding  = (const float*)d_in[1];
    const float* Wq = (const float*)d_in[2];
    const float* Wk = (const float*)d_in[3];
    const float* Wv = (const float*)d_in[4];
    const float* W0 = (const float*)d_in[5];
    const float* b0 = (const float*)d_in[6];
    const float* W1 = (const float*)d_in[7];
    const float* b1 = (const float*)d_in[8];
    float* out = (float*)d_out;

    const size_t ACT = (size_t)BATCH * NQ * DMODEL;   // 4M elements
    const size_t WEL = (size_t)DMODEL * DMODEL;       // 256K elements

    unsigned short* Xq   = (unsigned short*)d_ws;          // bf16 init_query
    unsigned short* Xe   = Xq + ACT;                       // bf16 embedding
    unsigned short* Wt   = Xe + ACT;                       // 5 transposed weights
    unsigned short* Qh   = Wt + 5 * WEL;                   // [bh][q][d]
    unsigned short* Kh   = Qh + ACT;                       // [bh][k][d]
    unsigned short* Vtb  = Kh + ACT;                       // [bh][d][k]
    unsigned short* attnb= Vtb + ACT;                      // [8192][512]
    unsigned short* ybuf = attnb + ACT;                    // [8192][512]
    float* colSrcp = (float*)(ybuf + ACT);                 // [bh][k]

    unsigned short* W0t = Wt + 3 * WEL;
    unsigned short* W1t = Wt + 4 * WEL;

    const int M = BATCH * NQ;  // 8192
    dim3 blk(256);
    dim3 blk512(512);
    dim3 gGemm(M / 128, DMODEL / 64);  // 64 x 8

    cast_x<<<dim3(ACT / 1024, 2), blk, 0, stream>>>(init_query, embedding, Xq, Xe);
    trans_w<<<dim3(16, 16, 5), blk, 0, stream>>>(Wq, Wk, Wv, W0, W1, Wt);

    gemm_qkv<<<dim3(M / 128, DMODEL / 64, 3), blk, 0, stream>>>(Xq, Xe, Wt, Qh, Kh, Vtb);

    attn_pass1<<<dim3(NKEY / 128, BH), blk512, 0, stream>>>(Qh, Kh, colSrcp);
    attn_pass2<<<dim3(NQ / 128, BH), blk512, 0, stream>>>(Qh, Kh, Vtb, colSrcp, attnb);

    gemm_bf16<2><<<gGemm, blk, 0, stream>>>(attnb, W0t, ybuf, b0, init_query, M, DMODEL, DMODEL);
    gemm_bf16<3><<<gGemm, blk, 0, stream>>>(ybuf, W1t, out, b1, nullptr, M, DMODEL, DMODEL);
}

// Round 6
// 226.056 us; speedup vs baseline: 2.5012x; 1.0048x over previous
//
#include <hip/hip_runtime.h>
#include <math.h>

#define BATCH 4
#define NQ 2048
#define NKEY 2048
#define DMODEL 512
#define NH 8
#define DHEAD 64
#define BH (BATCH * NH)

typedef __attribute__((ext_vector_type(8))) short short8;
typedef __attribute__((ext_vector_type(4))) float f32x4;

#define MFMA16(a, b, c) __builtin_amdgcn_mfma_f32_16x16x32_bf16((a), (b), (c), 0, 0, 0)

// f32 -> bf16 bits, round-to-nearest-even
static __device__ __forceinline__ unsigned short f2b(float f) {
    union { float f; unsigned u; } v; v.f = f;
    unsigned r = (v.u + 0x7fffu + ((v.u >> 16) & 1u)) >> 16;
    return (unsigned short)r;
}
// bf16 bits -> f32
static __device__ __forceinline__ float b2f(unsigned short u) {
    union { unsigned u; float f; } v; v.u = ((unsigned)u) << 16;
    return v.f;
}

// ---------------------------------------------------------------------------
// Cast both activations f32 -> bf16 (row-major [8192,512])
// ---------------------------------------------------------------------------
__launch_bounds__(256) __global__
void cast_x(const float* __restrict__ a, const float* __restrict__ b,
            unsigned short* __restrict__ da, unsigned short* __restrict__ db) {
    const float* s = blockIdx.y ? b : a;
    unsigned short* d = blockIdx.y ? db : da;
    size_t i = ((size_t)blockIdx.x * 256 + threadIdx.x) * 4;
    float4 v = *(const float4*)(s + i);
    ushort4 o;
    o.x = f2b(v.x); o.y = f2b(v.y); o.z = f2b(v.z); o.w = f2b(v.w);
    *(ushort4*)(d + i) = o;
}

// ---------------------------------------------------------------------------
// Transpose+cast the five 512x512 weights: Wt[n][k] = bf16(W[k][n])
// ---------------------------------------------------------------------------
__launch_bounds__(256) __global__
void trans_w(const float* __restrict__ w0, const float* __restrict__ w1,
             const float* __restrict__ w2, const float* __restrict__ w3,
             const float* __restrict__ w4, unsigned short* __restrict__ dst) {
    const float* src = (blockIdx.z == 0) ? w0 : (blockIdx.z == 1) ? w1 :
                       (blockIdx.z == 2) ? w2 : (blockIdx.z == 3) ? w3 : w4;
    unsigned short* out = dst + (size_t)blockIdx.z * DMODEL * DMODEL;
    __shared__ float t[32][33];
    const int tx = threadIdx.x & 31, ty = threadIdx.x >> 5;  // 32 x 8
    const int k0 = blockIdx.x * 32, n0 = blockIdx.y * 32;
    #pragma unroll
    for (int j = 0; j < 4; ++j)
        t[ty + j * 8][tx] = src[(size_t)(k0 + ty + j * 8) * DMODEL + n0 + tx];
    __syncthreads();
    #pragma unroll
    for (int j = 0; j < 4; ++j)
        out[(size_t)(n0 + ty + j * 8) * DMODEL + k0 + tx] = f2b(t[tx][ty + j * 8]);
}

// ---------------------------------------------------------------------------
// LDS-staged GEMM core: BM=128, BN=64, BK=64, 256 thr / 4 waves. (unchanged)
// ---------------------------------------------------------------------------
__device__ __forceinline__
void gemm_core(const unsigned short* __restrict__ A0,   // = A + mTile*K
               const unsigned short* __restrict__ B0,   // = Bt + n0*K
               int K, int tid, unsigned short* Al, unsigned short* Bl,
               f32x4 acc[2][4]) {
    const int w = tid >> 6, lane = tid & 63;
    const int l16 = lane & 15, q4 = lane >> 4;
    char* AlB = (char*)Al;
    char* BlB = (char*)Bl;
    const int srow = tid >> 3;           // 0..31
    const int scolb = (tid & 7) * 16;    // byte col 0..112
    const int skoff = (tid & 7) * 8;     // k-element offset

    f32x4 z = {0.f, 0.f, 0.f, 0.f};
    #pragma unroll
    for (int i = 0; i < 2; ++i)
        #pragma unroll
        for (int t = 0; t < 4; ++t) acc[i][t] = z;

    // prologue: stage regs for k0 = 0
    short8 ast[4], bst[2];
    #pragma unroll
    for (int c = 0; c < 4; ++c)
        ast[c] = *(const short8*)(A0 + (size_t)(c * 32 + srow) * K + skoff);
    #pragma unroll
    for (int c = 0; c < 2; ++c)
        bst[c] = *(const short8*)(B0 + (size_t)(c * 32 + srow) * K + skoff);

    for (int k0 = 0; k0 < K; k0 += 64) {
        __syncthreads();  // previous tile's fragment reads complete
        #pragma unroll
        for (int c = 0; c < 4; ++c) {
            const int row = c * 32 + srow;
            *(short8*)(AlB + row * 128 + (scolb ^ ((row & 7) << 4))) = ast[c];
        }
        #pragma unroll
        for (int c = 0; c < 2; ++c) {
            const int row = c * 32 + srow;
            *(short8*)(BlB + row * 128 + (scolb ^ ((row & 7) << 4))) = bst[c];
        }
        if (k0 + 64 < K) {  // prefetch next K-tile into regs (hides under compute)
            #pragma unroll
            for (int c = 0; c < 4; ++c)
                ast[c] = *(const short8*)(A0 + (size_t)(c * 32 + srow) * K + k0 + 64 + skoff);
            #pragma unroll
            for (int c = 0; c < 2; ++c)
                bst[c] = *(const short8*)(B0 + (size_t)(c * 32 + srow) * K + k0 + 64 + skoff);
        }
        __syncthreads();

        #pragma unroll
        for (int kk = 0; kk < 2; ++kk) {
            const int kb = kk * 64;  // byte base within 128B row
            const int rswA0 = ((w * 32 + l16) & 7) << 4;
            short8 a0 = *(const short8*)(AlB + (w * 32 + l16) * 128 + ((kb + q4 * 16) ^ rswA0));
            short8 a1 = *(const short8*)(AlB + (w * 32 + 16 + l16) * 128 + ((kb + q4 * 16) ^ rswA0));
            short8 bfr[4];
            #pragma unroll
            for (int t = 0; t < 4; ++t) {
                const int row = t * 16 + l16;
                bfr[t] = *(const short8*)(BlB + row * 128 + ((kb + q4 * 16) ^ ((row & 7) << 4)));
            }
            #pragma unroll
            for (int t = 0; t < 4; ++t) {
                acc[0][t] = MFMA16(a0, bfr[t], acc[0][t]);
                acc[1][t] = MFMA16(a1, bfr[t], acc[1][t]);
            }
        }
    }
}

// ---------------------------------------------------------------------------
// Fused QKV projection: grid.z selects {Q, K, V}.  (unchanged)
// ---------------------------------------------------------------------------
__launch_bounds__(256) __global__
void gemm_qkv(const unsigned short* __restrict__ Xq,
              const unsigned short* __restrict__ Xe,
              const unsigned short* __restrict__ Wt,
              unsigned short* __restrict__ Qh,
              unsigned short* __restrict__ Kh,
              unsigned short* __restrict__ Vtb) {
    __shared__ unsigned short Al[128 * 64];  // 16KB
    __shared__ unsigned short Bl[64 * 64];   // 8KB
    const int tid = threadIdx.x;
    const int zsel = blockIdx.z;
    const int K = DMODEL;
    const unsigned short* A = (zsel == 0) ? Xq : Xe;
    const unsigned short* B0 = Wt + (size_t)zsel * DMODEL * DMODEL + (size_t)(blockIdx.y * 64) * K;
    const unsigned short* A0 = A + (size_t)(blockIdx.x * 128) * K;

    f32x4 acc[2][4];
    gemm_core(A0, B0, K, tid, Al, Bl, acc);

    const int w = tid >> 6, lane = tid & 63;
    const int l16 = lane & 15, q4 = lane >> 4;
    const int mBase = blockIdx.x * 128 + w * 32;
    const int n0 = blockIdx.y * 64;

    if (zsel < 2) {
        unsigned short* out = (zsel == 0) ? Qh : Kh;
        #pragma unroll
        for (int i = 0; i < 2; ++i)
            #pragma unroll
            for (int t = 0; t < 4; ++t)
                #pragma unroll
                for (int r = 0; r < 4; ++r) {
                    const int m = mBase + i * 16 + q4 * 4 + r;
                    const int n = n0 + t * 16 + l16;
                    out[(((size_t)(m >> 11) * NH + (n >> 6)) * NQ + (m & 2047)) * DHEAD + (n & 63)] = f2b(acc[i][t][r]);
                }
    } else {
        #pragma unroll
        for (int i = 0; i < 2; ++i)
            #pragma unroll
            for (int t = 0; t < 4; ++t) {
                const int m0 = mBase + i * 16 + q4 * 4;  // 4-aligned
                const int n = n0 + t * 16 + l16;
                ushort4 p;
                p.x = f2b(acc[i][t][0]); p.y = f2b(acc[i][t][1]);
                p.z = f2b(acc[i][t][2]); p.w = f2b(acc[i][t][3]);
                *(ushort4*)(Vtb + (((size_t)(m0 >> 11) * NH + (n >> 6)) * DHEAD + (n & 63)) * NKEY + (m0 & 2047)) = p;
            }
    }
}

// ---------------------------------------------------------------------------
// LDS-staged GEMM, modes 2/3.  (unchanged)
// ---------------------------------------------------------------------------
template <int MODE>
__launch_bounds__(256) __global__
void gemm_bf16(const unsigned short* __restrict__ A,
               const unsigned short* __restrict__ Bt,
               void* __restrict__ Cout, const float* __restrict__ bias,
               const float* __restrict__ resid, int M, int N, int K) {
    __shared__ unsigned short Al[128 * 64];
    __shared__ unsigned short Bl[64 * 64];
    const int tid = threadIdx.x;
    const unsigned short* A0 = A + (size_t)(blockIdx.x * 128) * K;
    const unsigned short* B0 = Bt + (size_t)(blockIdx.y * 64) * K;

    f32x4 acc[2][4];
    gemm_core(A0, B0, K, tid, Al, Bl, acc);

    const int w = tid >> 6, lane = tid & 63;
    const int l16 = lane & 15, q4 = lane >> 4;
    const int mBase = blockIdx.x * 128 + w * 32;
    const int n0 = blockIdx.y * 64;

    #pragma unroll
    for (int i = 0; i < 2; ++i)
        #pragma unroll
        for (int t = 0; t < 4; ++t)
            #pragma unroll
            for (int r = 0; r < 4; ++r) {
                const int m = mBase + i * 16 + q4 * 4 + r;
                const int n = n0 + t * 16 + l16;
                float v = acc[i][t][r];
                if (MODE == 2) {
                    ((unsigned short*)Cout)[(size_t)m * N + n] = f2b(resid[(size_t)m * N + n] - (v + bias[n]));
                } else {
                    ((float*)Cout)[(size_t)m * N + n] = v + bias[n];
                }
            }
}

// ---------------------------------------------------------------------------
// Pass 1: colSrcp[bh][k] = 1 / sum_q exp(S[q,k]); also cbuf = bf16(colSrcp).
// 512 thr / 8 waves; Q-tiles double-buffered; one barrier/iter.
// ---------------------------------------------------------------------------
__launch_bounds__(512) __global__
void attn_pass1(const unsigned short* __restrict__ Qh,
                const unsigned short* __restrict__ Kh,
                float* __restrict__ colSrcp,
                unsigned short* __restrict__ cbuf) {
    __shared__ unsigned short Qt[2][64 * 64];  // 2 x 8 KB, swizzled [q][d]
    const int tid = threadIdx.x;
    const int w = tid >> 6, lane = tid & 63;
    const int l16 = lane & 15, q4 = lane >> 4;
    const int bh = blockIdx.y;
    const int kcol0 = blockIdx.x * 128 + w * 16;

    short8 bk0, bk1;
    {
        const unsigned short* Krow = Kh + ((size_t)bh * NKEY + kcol0 + l16) * DHEAD;
        bk0 = *(const short8*)(Krow + q4 * 8);
        bk1 = *(const short8*)(Krow + 32 + q4 * 8);
    }
    const unsigned short* Qb = Qh + (size_t)bh * NQ * DHEAD;
    const int srow = tid >> 3;            // 0..63 (one row-chunk per thread)
    const int skoff = (tid & 7) * 8;      // k-element offset within row
    const int ssw = ((tid & 7) * 16) ^ ((srow & 7) << 4);
    const int rsw = (l16 & 7) << 4;

    f32x4 z = {0.f, 0.f, 0.f, 0.f};
    float csum = 0.f;

    // prologue: tile0 -> buf0; tile1 into regs
    short8 qst = *(const short8*)(Qb + (size_t)srow * DHEAD + skoff);
    *(short8*)((char*)Qt[0] + srow * 128 + ssw) = qst;
    qst = *(const short8*)(Qb + (size_t)(64 + srow) * DHEAD + skoff);
    __syncthreads();

    for (int it = 0; it < 32; ++it) {
        const int q0 = it * 64;
        char* QtB = (char*)Qt[it & 1];
        char* QtN = (char*)Qt[(it & 1) ^ 1];

        // stage tile it+1 into the idle buffer; prefetch tile it+2
        if (it < 31) {
            *(short8*)(QtN + srow * 128 + ssw) = qst;
            if (it < 30)
                qst = *(const short8*)(Qb + (size_t)(q0 + 128 + srow) * DHEAD + skoff);
        }

        #pragma unroll
        for (int qi = 0; qi < 4; ++qi) {
            const int row = qi * 16 + l16;
            short8 a0 = *(const short8*)(QtB + row * 128 + ((q4 * 16) ^ rsw));
            short8 a1 = *(const short8*)(QtB + row * 128 + ((64 + q4 * 16) ^ rsw));
            __builtin_amdgcn_s_setprio(1);
            f32x4 s = MFMA16(a0, bk0, z);
            s = MFMA16(a1, bk1, s);
            __builtin_amdgcn_s_setprio(0);
            csum += __expf(s[0]) + __expf(s[1]) + __expf(s[2]) + __expf(s[3]);
        }
        __syncthreads();
    }
    csum += __shfl_xor(csum, 16, 64);
    csum += __shfl_xor(csum, 32, 64);
    if (q4 == 0) {
        const float c = 1.0f / csum;
        colSrcp[(size_t)bh * NKEY + kcol0 + l16] = c;
        cbuf[(size_t)bh * NKEY + kcol0 + l16] = f2b(c);
    }
}

// ---------------------------------------------------------------------------
// Scale V rows by colSrcp in place: Vtb[bh][d][k] *= colSrcp[bh][k]  (bf16)
// ---------------------------------------------------------------------------
__launch_bounds__(256) __global__
void scale_v(unsigned short* __restrict__ Vtb, const float* __restrict__ colSrcp) {
    const size_t t8 = ((size_t)blockIdx.x * 256 + threadIdx.x) * 8;
    const int k = (int)(t8 & (NKEY - 1));
    const int bh = (int)(t8 >> 17);  // / (DHEAD * NKEY)
    const float* cs = colSrcp + ((size_t)bh << 11) + k;
    short8 v = *(const short8*)(Vtb + t8);
    float4 c0 = *(const float4*)cs;
    float4 c1 = *(const float4*)(cs + 4);
    short8 o;
    o[0] = (short)f2b(b2f((unsigned short)v[0]) * c0.x);
    o[1] = (short)f2b(b2f((unsigned short)v[1]) * c0.y);
    o[2] = (short)f2b(b2f((unsigned short)v[2]) * c0.z);
    o[3] = (short)f2b(b2f((unsigned short)v[3]) * c0.w);
    o[4] = (short)f2b(b2f((unsigned short)v[4]) * c1.x);
    o[5] = (short)f2b(b2f((unsigned short)v[5]) * c1.y);
    o[6] = (short)f2b(b2f((unsigned short)v[6]) * c1.z);
    o[7] = (short)f2b(b2f((unsigned short)v[7]) * c1.w);
    *(short8*)(Vtb + t8) = o;
}

// ---------------------------------------------------------------------------
// Pass 2 (restructured): F = exp(S); O = F @ (cV); rq = F @ c (ones-trick
// via extra MFMA against broadcast bf16(c)); attnb = bf16(O / (1e-12 + rq)).
// Swapped QK (mfma(K,Q) -> S^T): thread holds 4 CONSECUTIVE k per q, so E is
// written as 2 x ds_write_b64 per sub-tile (was 8 x ds_write_b16). E single-
// buffered per wave. K/V tiles double-buffered as round 4; one barrier/iter.
// Grid: (NQ/128, BH) = 512 blocks, 512 thr / 8 waves.
// ---------------------------------------------------------------------------
__launch_bounds__(512) __global__
void attn_pass2(const unsigned short* __restrict__ Qh,
                const unsigned short* __restrict__ Kh,
                const unsigned short* __restrict__ Vt,   // pre-scaled by c
                const unsigned short* __restrict__ cb,   // bf16 colSrcp
                unsigned short* __restrict__ attnb) {
    __shared__ unsigned short Kt[2][64 * 64];      // 16 KB
    __shared__ unsigned short Vtile[2][64 * 64];   // 16 KB
    __shared__ unsigned short Elds[8][16][40];     // 10 KB, single buf per wave
    const int tid = threadIdx.x;
    const int w = tid >> 6, lane = tid & 63;
    const int l16 = lane & 15, q4 = lane >> 4;
    const int bh = blockIdx.y;
    const int b = bh >> 3, h = bh & 7;
    const int q0w = blockIdx.x * 128 + w * 16;

    short8 aq0, aq1;
    {
        const unsigned short* Qrow = Qh + ((size_t)bh * NQ + q0w + l16) * DHEAD;
        aq0 = *(const short8*)(Qrow + q4 * 8);
        aq1 = *(const short8*)(Qrow + 32 + q4 * 8);
    }
    const unsigned short* Kb = Kh + (size_t)bh * NKEY * DHEAD;
    const unsigned short* Vb = Vt + (size_t)bh * DHEAD * NKEY;
    const unsigned short* cbb = cb + (size_t)bh * NKEY;
    char* Ew = (char*)&Elds[w][0][0];

    const int srow = tid >> 3;            // 0..63
    const int skoff = (tid & 7) * 8;
    const int ssw = ((tid & 7) * 16) ^ ((srow & 7) << 4);
    const int rsw = (l16 & 7) << 4;

    f32x4 z = {0.f, 0.f, 0.f, 0.f};
    f32x4 o[4];
    #pragma unroll
    for (int t = 0; t < 4; ++t) o[t] = z;
    f32x4 o5 = z;  // rq accumulator: o5[r] = sum_k F[q=l16][k]*c[k] per r-group

    // prologue: tile0 -> buf0; tile1 into regs
    short8 kst = *(const short8*)(Kb + (size_t)srow * DHEAD + skoff);
    short8 vst = *(const short8*)(Vb + (size_t)srow * NKEY + skoff);
    *(short8*)((char*)Kt[0] + srow * 128 + ssw) = kst;
    *(short8*)((char*)Vtile[0] + srow * 128 + ssw) = vst;
    kst = *(const short8*)(Kb + (size_t)(64 + srow) * DHEAD + skoff);
    vst = *(const short8*)(Vb + (size_t)srow * NKEY + 64 + skoff);
    __syncthreads();

    for (int it = 0; it < 32; ++it) {
        const int k0 = it * 64;
        char* KtB = (char*)Kt[it & 1];
        char* VtB = (char*)Vtile[it & 1];
        char* KtN = (char*)Kt[(it & 1) ^ 1];
        char* VtN = (char*)Vtile[(it & 1) ^ 1];

        // stage tile it+1 into idle buffers; prefetch tile it+2 into regs
        if (it < 31) {
            *(short8*)(KtN + srow * 128 + ssw) = kst;
            *(short8*)(VtN + srow * 128 + ssw) = vst;
            if (it < 30) {
                kst = *(const short8*)(Kb + (size_t)(k0 + 128 + srow) * DHEAD + skoff);
                vst = *(const short8*)(Vb + (size_t)srow * NKEY + (k0 + 128) + skoff);
            }
        }

        #pragma unroll
        for (int sub = 0; sub < 2; ++sub) {
            const int kb = k0 + sub * 32;
            // K fragments (A-operand: rows = k)
            short8 bk[2][2];
            #pragma unroll
            for (int jt = 0; jt < 2; ++jt) {
                const int row = sub * 32 + jt * 16 + l16;
                bk[jt][0] = *(const short8*)(KtB + row * 128 + ((q4 * 16) ^ rsw));
                bk[jt][1] = *(const short8*)(KtB + row * 128 + ((64 + q4 * 16) ^ rsw));
            }
            // V fragments (B-operand: cols = d)
            short8 bv[4];
            #pragma unroll
            for (int t = 0; t < 4; ++t) {
                const int row = t * 16 + l16;
                bv[t] = *(const short8*)(VtB + row * 128 + ((sub * 64 + q4 * 16) ^ rsw));
            }
            // broadcast c fragment (B[col][k] = c[k] for all cols)
            short8 bv5 = *(const short8*)(cbb + kb + q4 * 8);

            // Swapped QK: S^T -> thread holds S[q=l16][k = kb + jt*16 + q4*4 + r]
            #pragma unroll
            for (int jt = 0; jt < 2; ++jt) {
                __builtin_amdgcn_s_setprio(1);
                f32x4 st = MFMA16(bk[jt][0], aq0, z);
                st = MFMA16(bk[jt][1], aq1, st);
                __builtin_amdgcn_s_setprio(0);
                uint2 p;
                p.x = (unsigned)f2b(__expf(st[0])) | ((unsigned)f2b(__expf(st[1])) << 16);
                p.y = (unsigned)f2b(__expf(st[2])) | ((unsigned)f2b(__expf(st[3])) << 16);
                // E[q=l16][k-local = jt*16 + 4*q4 .. +3], row stride 80 B
                *(uint2*)(Ew + l16 * 80 + jt * 32 + q4 * 8) = p;
            }
            short8 ea = *(const short8*)(Ew + l16 * 80 + q4 * 16);
            __builtin_amdgcn_s_setprio(1);
            #pragma unroll
            for (int t = 0; t < 4; ++t)
                o[t] = MFMA16(ea, bv[t], o[t]);
            o5 = MFMA16(ea, bv5, o5);
            __builtin_amdgcn_s_setprio(0);
        }
        __syncthreads();
    }

    float rr[4];
    #pragma unroll
    for (int r = 0; r < 4; ++r) rr[r] = 1.0f / (1e-12f + o5[r]);
    #pragma unroll
    for (int t = 0; t < 4; ++t)
        #pragma unroll
        for (int r = 0; r < 4; ++r) {
            const int q = q0w + q4 * 4 + r;
            attnb[((size_t)b * NQ + q) * DMODEL + h * DHEAD + t * 16 + l16] =
                f2b(o[t][r] * rr[r]);
        }
}

// ---------------------------------------------------------------------------
extern "C" void kernel_launch(void* const* d_in, const int* in_sizes, int n_in,
                              void* d_out, int out_size, void* d_ws, size_t ws_size,
                              hipStream_t stream) {
    const float* init_query = (const float*)d_in[0];
    const float* embedding  = (const float*)d_in[1];
    const float* Wq = (const float*)d_in[2];
    const float* Wk = (const float*)d_in[3];
    const float* Wv = (const float*)d_in[4];
    const float* W0 = (const float*)d_in[5];
    const float* b0 = (const float*)d_in[6];
    const float* W1 = (const float*)d_in[7];
    const float* b1 = (const float*)d_in[8];
    float* out = (float*)d_out;

    const size_t ACT = (size_t)BATCH * NQ * DMODEL;   // 4M elements
    const size_t WEL = (size_t)DMODEL * DMODEL;       // 256K elements

    unsigned short* Xq   = (unsigned short*)d_ws;          // bf16 init_query
    unsigned short* Xe   = Xq + ACT;                       // bf16 embedding
    unsigned short* Wt   = Xe + ACT;                       // 5 transposed weights
    unsigned short* Qh   = Wt + 5 * WEL;                   // [bh][q][d]
    unsigned short* Kh   = Qh + ACT;                       // [bh][k][d]
    unsigned short* Vtb  = Kh + ACT;                       // [bh][d][k]
    unsigned short* attnb= Vtb + ACT;                      // [8192][512]
    unsigned short* ybuf = attnb + ACT;                    // [8192][512]
    float* colSrcp = (float*)(ybuf + ACT);                 // [bh][k] f32

    // cbuf (bf16 colSrcp, 128 KB) ALIASES ybuf: ybuf is dead until the W0-GEMM,
    // which launches after pass2 has consumed cbuf. Keeps workspace footprint
    // identical to the proven rounds 0-4 layout.
    unsigned short* cbuf = ybuf;

    unsigned short* W0t = Wt + 3 * WEL;
    unsigned short* W1t = Wt + 4 * WEL;

    const int M = BATCH * NQ;  // 8192
    dim3 blk(256);
    dim3 blk512(512);
    dim3 gGemm(M / 128, DMODEL / 64);  // 64 x 8

    cast_x<<<dim3(ACT / 1024, 2), blk, 0, stream>>>(init_query, embedding, Xq, Xe);
    trans_w<<<dim3(16, 16, 5), blk, 0, stream>>>(Wq, Wk, Wv, W0, W1, Wt);

    gemm_qkv<<<dim3(M / 128, DMODEL / 64, 3), blk, 0, stream>>>(Xq, Xe, Wt, Qh, Kh, Vtb);

    attn_pass1<<<dim3(NKEY / 128, BH), blk512, 0, stream>>>(Qh, Kh, colSrcp, cbuf);
    scale_v<<<dim3(ACT / 2048), blk, 0, stream>>>(Vtb, colSrcp);
    attn_pass2<<<dim3(NQ / 128, BH), blk512, 0, stream>>>(Qh, Kh, Vtb, cbuf, attnb);

    gemm_bf16<2><<<gGemm, blk, 0, stream>>>(attnb, W0t, ybuf, b0, init_query, M, DMODEL, DMODEL);
    gemm_bf16<3><<<gGemm, blk, 0, stream>>>(ybuf, W1t, out, b1, nullptr, M, DMODEL, DMODEL);
}

// Round 7
// 209.339 us; speedup vs baseline: 2.7009x; 1.0799x over previous
//
#include <hip/hip_runtime.h>
#include <math.h>

#define BATCH 4
#define NQ 2048
#define NKEY 2048
#define DMODEL 512
#define NH 8
#define DHEAD 64
#define BH (BATCH * NH)

typedef __attribute__((ext_vector_type(8))) short short8;
typedef __attribute__((ext_vector_type(4))) float f32x4;

#define MFMA16(a, b, c) __builtin_amdgcn_mfma_f32_16x16x32_bf16((a), (b), (c), 0, 0, 0)

// f32 -> bf16 bits, round-to-nearest-even
static __device__ __forceinline__ unsigned short f2b(float f) {
    union { float f; unsigned u; } v; v.f = f;
    unsigned r = (v.u + 0x7fffu + ((v.u >> 16) & 1u)) >> 16;
    return (unsigned short)r;
}
// bf16 bits -> f32
static __device__ __forceinline__ float b2f(unsigned short u) {
    union { unsigned u; float f; } v; v.u = ((unsigned)u) << 16;
    return v.f;
}
// pack 2 f32 -> 2 bf16 (RNE, identical to f2b) in one instruction
static __device__ __forceinline__ unsigned pkbf(float lo, float hi) {
    unsigned r;
    asm("v_cvt_pk_bf16_f32 %0, %1, %2" : "=v"(r) : "v"(lo), "v"(hi));
    return r;
}
static __device__ __forceinline__ float ex2(float x) {
    return __builtin_amdgcn_exp2f(x);
}

// ---------------------------------------------------------------------------
// Cast both activations f32 -> bf16 (row-major [8192,512])
// ---------------------------------------------------------------------------
__launch_bounds__(256) __global__
void cast_x(const float* __restrict__ a, const float* __restrict__ b,
            unsigned short* __restrict__ da, unsigned short* __restrict__ db) {
    const float* s = blockIdx.y ? b : a;
    unsigned short* d = blockIdx.y ? db : da;
    size_t i = ((size_t)blockIdx.x * 256 + threadIdx.x) * 4;
    float4 v = *(const float4*)(s + i);
    ushort4 o;
    o.x = f2b(v.x); o.y = f2b(v.y); o.z = f2b(v.z); o.w = f2b(v.w);
    *(ushort4*)(d + i) = o;
}

// ---------------------------------------------------------------------------
// Transpose+cast the five 512x512 weights: Wt[n][k] = bf16(W[k][n]).
// Wq (z==0) is pre-scaled by log2(e) so S' = S*log2e and exp(S) = exp2(S') —
// removes the v_mul inside __expf in BOTH attention passes.
// ---------------------------------------------------------------------------
__launch_bounds__(256) __global__
void trans_w(const float* __restrict__ w0, const float* __restrict__ w1,
             const float* __restrict__ w2, const float* __restrict__ w3,
             const float* __restrict__ w4, unsigned short* __restrict__ dst) {
    const float* src = (blockIdx.z == 0) ? w0 : (blockIdx.z == 1) ? w1 :
                       (blockIdx.z == 2) ? w2 : (blockIdx.z == 3) ? w3 : w4;
    unsigned short* out = dst + (size_t)blockIdx.z * DMODEL * DMODEL;
    const float sc = (blockIdx.z == 0) ? 1.44269504088896340736f : 1.0f;
    __shared__ float t[32][33];
    const int tx = threadIdx.x & 31, ty = threadIdx.x >> 5;  // 32 x 8
    const int k0 = blockIdx.x * 32, n0 = blockIdx.y * 32;
    #pragma unroll
    for (int j = 0; j < 4; ++j)
        t[ty + j * 8][tx] = src[(size_t)(k0 + ty + j * 8) * DMODEL + n0 + tx];
    __syncthreads();
    #pragma unroll
    for (int j = 0; j < 4; ++j)
        out[(size_t)(n0 + ty + j * 8) * DMODEL + k0 + tx] = f2b(t[tx][ty + j * 8] * sc);
}

// ---------------------------------------------------------------------------
// LDS-staged GEMM core: BM=128, BN=64, BK=64, 256 thr / 4 waves.
// NOW double-buffered: ONE barrier per K-tile (was 2). MFMA order unchanged
// (k ascending) -> bit-identical accumulation.
// ---------------------------------------------------------------------------
__device__ __forceinline__
void gemm_core(const unsigned short* __restrict__ A0,   // = A + mTile*K
               const unsigned short* __restrict__ B0,   // = Bt + n0*K
               int K, int tid, unsigned short* Al, unsigned short* Bl,
               f32x4 acc[2][4]) {
    const int w = tid >> 6, lane = tid & 63;
    const int l16 = lane & 15, q4 = lane >> 4;
    const int srow = tid >> 3;           // 0..31
    const int scolb = (tid & 7) * 16;    // byte col 0..112
    const int skoff = (tid & 7) * 8;     // k-element offset

    f32x4 z = {0.f, 0.f, 0.f, 0.f};
    #pragma unroll
    for (int i = 0; i < 2; ++i)
        #pragma unroll
        for (int t = 0; t < 4; ++t) acc[i][t] = z;

    short8 ast[4], bst[2];
    // tile 0 -> regs -> buf0
    #pragma unroll
    for (int c = 0; c < 4; ++c)
        ast[c] = *(const short8*)(A0 + (size_t)(c * 32 + srow) * K + skoff);
    #pragma unroll
    for (int c = 0; c < 2; ++c)
        bst[c] = *(const short8*)(B0 + (size_t)(c * 32 + srow) * K + skoff);
    {
        char* AlB = (char*)Al;
        char* BlB = (char*)Bl;
        #pragma unroll
        for (int c = 0; c < 4; ++c) {
            const int row = c * 32 + srow;
            *(short8*)(AlB + row * 128 + (scolb ^ ((row & 7) << 4))) = ast[c];
        }
        #pragma unroll
        for (int c = 0; c < 2; ++c) {
            const int row = c * 32 + srow;
            *(short8*)(BlB + row * 128 + (scolb ^ ((row & 7) << 4))) = bst[c];
        }
    }
    // prefetch tile 1 into regs
    #pragma unroll
    for (int c = 0; c < 4; ++c)
        ast[c] = *(const short8*)(A0 + (size_t)(c * 32 + srow) * K + 64 + skoff);
    #pragma unroll
    for (int c = 0; c < 2; ++c)
        bst[c] = *(const short8*)(B0 + (size_t)(c * 32 + srow) * K + 64 + skoff);
    __syncthreads();

    const int NT = K >> 6;  // 8
    for (int t = 0; t < NT; ++t) {
        char* AlB = (char*)(Al + (t & 1) * (128 * 64));
        char* BlB = (char*)(Bl + (t & 1) * (64 * 64));
        if (t + 1 < NT) {  // stage tile t+1 into idle buffer; prefetch t+2
            char* AlN = (char*)(Al + ((t + 1) & 1) * (128 * 64));
            char* BlN = (char*)(Bl + ((t + 1) & 1) * (64 * 64));
            #pragma unroll
            for (int c = 0; c < 4; ++c) {
                const int row = c * 32 + srow;
                *(short8*)(AlN + row * 128 + (scolb ^ ((row & 7) << 4))) = ast[c];
            }
            #pragma unroll
            for (int c = 0; c < 2; ++c) {
                const int row = c * 32 + srow;
                *(short8*)(BlN + row * 128 + (scolb ^ ((row & 7) << 4))) = bst[c];
            }
            if (t + 2 < NT) {
                const int kn = (t + 2) * 64;
                #pragma unroll
                for (int c = 0; c < 4; ++c)
                    ast[c] = *(const short8*)(A0 + (size_t)(c * 32 + srow) * K + kn + skoff);
                #pragma unroll
                for (int c = 0; c < 2; ++c)
                    bst[c] = *(const short8*)(B0 + (size_t)(c * 32 + srow) * K + kn + skoff);
            }
        }

        #pragma unroll
        for (int kk = 0; kk < 2; ++kk) {
            const int kb = kk * 64;  // byte base within 128B row
            const int rswA0 = ((w * 32 + l16) & 7) << 4;
            short8 a0 = *(const short8*)(AlB + (w * 32 + l16) * 128 + ((kb + q4 * 16) ^ rswA0));
            short8 a1 = *(const short8*)(AlB + (w * 32 + 16 + l16) * 128 + ((kb + q4 * 16) ^ rswA0));
            short8 bfr[4];
            #pragma unroll
            for (int t2 = 0; t2 < 4; ++t2) {
                const int row = t2 * 16 + l16;
                bfr[t2] = *(const short8*)(BlB + row * 128 + ((kb + q4 * 16) ^ ((row & 7) << 4)));
            }
            #pragma unroll
            for (int t2 = 0; t2 < 4; ++t2) {
                acc[0][t2] = MFMA16(a0, bfr[t2], acc[0][t2]);
                acc[1][t2] = MFMA16(a1, bfr[t2], acc[1][t2]);
            }
        }
        __syncthreads();
    }
}

// ---------------------------------------------------------------------------
// Fused QKV projection: grid.z selects {Q, K, V}.
// ---------------------------------------------------------------------------
__launch_bounds__(256) __global__
void gemm_qkv(const unsigned short* __restrict__ Xq,
              const unsigned short* __restrict__ Xe,
              const unsigned short* __restrict__ Wt,
              unsigned short* __restrict__ Qh,
              unsigned short* __restrict__ Kh,
              unsigned short* __restrict__ Vtb) {
    __shared__ unsigned short Al[2][128 * 64];  // 32KB
    __shared__ unsigned short Bl[2][64 * 64];   // 16KB
    const int tid = threadIdx.x;
    const int zsel = blockIdx.z;
    const int K = DMODEL;
    const unsigned short* A = (zsel == 0) ? Xq : Xe;
    const unsigned short* B0 = Wt + (size_t)zsel * DMODEL * DMODEL + (size_t)(blockIdx.y * 64) * K;
    const unsigned short* A0 = A + (size_t)(blockIdx.x * 128) * K;

    f32x4 acc[2][4];
    gemm_core(A0, B0, K, tid, &Al[0][0], &Bl[0][0], acc);

    const int w = tid >> 6, lane = tid & 63;
    const int l16 = lane & 15, q4 = lane >> 4;
    const int mBase = blockIdx.x * 128 + w * 32;
    const int n0 = blockIdx.y * 64;

    if (zsel < 2) {
        unsigned short* out = (zsel == 0) ? Qh : Kh;
        #pragma unroll
        for (int i = 0; i < 2; ++i)
            #pragma unroll
            for (int t = 0; t < 4; ++t)
                #pragma unroll
                for (int r = 0; r < 4; ++r) {
                    const int m = mBase + i * 16 + q4 * 4 + r;
                    const int n = n0 + t * 16 + l16;
                    out[(((size_t)(m >> 11) * NH + (n >> 6)) * NQ + (m & 2047)) * DHEAD + (n & 63)] = f2b(acc[i][t][r]);
                }
    } else {
        #pragma unroll
        for (int i = 0; i < 2; ++i)
            #pragma unroll
            for (int t = 0; t < 4; ++t) {
                const int m0 = mBase + i * 16 + q4 * 4;  // 4-aligned
                const int n = n0 + t * 16 + l16;
                ushort4 p;
                p.x = f2b(acc[i][t][0]); p.y = f2b(acc[i][t][1]);
                p.z = f2b(acc[i][t][2]); p.w = f2b(acc[i][t][3]);
                *(ushort4*)(Vtb + (((size_t)(m0 >> 11) * NH + (n >> 6)) * DHEAD + (n & 63)) * NKEY + (m0 & 2047)) = p;
            }
    }
}

// ---------------------------------------------------------------------------
// LDS-staged GEMM, modes 2/3.
// ---------------------------------------------------------------------------
template <int MODE>
__launch_bounds__(256) __global__
void gemm_bf16(const unsigned short* __restrict__ A,
               const unsigned short* __restrict__ Bt,
               void* __restrict__ Cout, const float* __restrict__ bias,
               const float* __restrict__ resid, int M, int N, int K) {
    __shared__ unsigned short Al[2][128 * 64];
    __shared__ unsigned short Bl[2][64 * 64];
    const int tid = threadIdx.x;
    const unsigned short* A0 = A + (size_t)(blockIdx.x * 128) * K;
    const unsigned short* B0 = Bt + (size_t)(blockIdx.y * 64) * K;

    f32x4 acc[2][4];
    gemm_core(A0, B0, K, tid, &Al[0][0], &Bl[0][0], acc);

    const int w = tid >> 6, lane = tid & 63;
    const int l16 = lane & 15, q4 = lane >> 4;
    const int mBase = blockIdx.x * 128 + w * 32;
    const int n0 = blockIdx.y * 64;

    #pragma unroll
    for (int i = 0; i < 2; ++i)
        #pragma unroll
        for (int t = 0; t < 4; ++t)
            #pragma unroll
            for (int r = 0; r < 4; ++r) {
                const int m = mBase + i * 16 + q4 * 4 + r;
                const int n = n0 + t * 16 + l16;
                float v = acc[i][t][r];
                if (MODE == 2) {
                    ((unsigned short*)Cout)[(size_t)m * N + n] = f2b(resid[(size_t)m * N + n] - (v + bias[n]));
                } else {
                    ((float*)Cout)[(size_t)m * N + n] = v + bias[n];
                }
            }
}

// ---------------------------------------------------------------------------
// Pass 1: colSrcp[bh][k] = 1 / sum_q exp2(S'[q,k]); cbuf = bf16(colSrcp).
// 512 thr / 8 waves. NOW 128-q tiles (2x16KB dbuf LDS): halves barrier count.
// csum accumulation order identical to the 64-q version.
// ---------------------------------------------------------------------------
__launch_bounds__(512) __global__
void attn_pass1(const unsigned short* __restrict__ Qh,
                const unsigned short* __restrict__ Kh,
                float* __restrict__ colSrcp,
                unsigned short* __restrict__ cbuf) {
    __shared__ unsigned short Qt[2][128 * 64];  // 2 x 16 KB, swizzled [q][d]
    const int tid = threadIdx.x;
    const int w = tid >> 6, lane = tid & 63;
    const int l16 = lane & 15, q4 = lane >> 4;
    const int bh = blockIdx.y;
    const int kcol0 = blockIdx.x * 128 + w * 16;

    short8 bk0, bk1;
    {
        const unsigned short* Krow = Kh + ((size_t)bh * NKEY + kcol0 + l16) * DHEAD;
        bk0 = *(const short8*)(Krow + q4 * 8);
        bk1 = *(const short8*)(Krow + 32 + q4 * 8);
    }
    const unsigned short* Qb = Qh + (size_t)bh * NQ * DHEAD;
    const int srow = tid >> 3;            // 0..63
    const int skoff = (tid & 7) * 8;
    const int ssw = ((tid & 7) * 16) ^ ((srow & 7) << 4);  // (srow+64)&7 == srow&7
    const int rsw = (l16 & 7) << 4;

    f32x4 z = {0.f, 0.f, 0.f, 0.f};
    float csum = 0.f;

    // prologue: tile0 (q 0..127) -> buf0; tile1 into regs
    short8 qa = *(const short8*)(Qb + (size_t)srow * DHEAD + skoff);
    short8 qb = *(const short8*)(Qb + (size_t)(64 + srow) * DHEAD + skoff);
    *(short8*)((char*)Qt[0] + srow * 128 + ssw) = qa;
    *(short8*)((char*)Qt[0] + (64 + srow) * 128 + ssw) = qb;
    qa = *(const short8*)(Qb + (size_t)(128 + srow) * DHEAD + skoff);
    qb = *(const short8*)(Qb + (size_t)(192 + srow) * DHEAD + skoff);
    __syncthreads();

    for (int it = 0; it < 16; ++it) {
        const int q0 = it * 128;
        char* QtB = (char*)Qt[it & 1];
        char* QtN = (char*)Qt[(it & 1) ^ 1];

        if (it < 15) {
            *(short8*)(QtN + srow * 128 + ssw) = qa;
            *(short8*)(QtN + (64 + srow) * 128 + ssw) = qb;
            if (it < 14) {
                qa = *(const short8*)(Qb + (size_t)(q0 + 256 + srow) * DHEAD + skoff);
                qb = *(const short8*)(Qb + (size_t)(q0 + 320 + srow) * DHEAD + skoff);
            }
        }

        #pragma unroll
        for (int qi = 0; qi < 8; ++qi) {
            const int row = qi * 16 + l16;
            short8 a0 = *(const short8*)(QtB + row * 128 + ((q4 * 16) ^ rsw));
            short8 a1 = *(const short8*)(QtB + row * 128 + ((64 + q4 * 16) ^ rsw));
            __builtin_amdgcn_s_setprio(1);
            f32x4 s = MFMA16(a0, bk0, z);
            s = MFMA16(a1, bk1, s);
            __builtin_amdgcn_s_setprio(0);
            csum += ex2(s[0]) + ex2(s[1]) + ex2(s[2]) + ex2(s[3]);
        }
        __syncthreads();
    }
    csum += __shfl_xor(csum, 16, 64);
    csum += __shfl_xor(csum, 32, 64);
    if (q4 == 0) {
        const float c = 1.0f / csum;
        colSrcp[(size_t)bh * NKEY + kcol0 + l16] = c;
        cbuf[(size_t)bh * NKEY + kcol0 + l16] = f2b(c);
    }
}

// ---------------------------------------------------------------------------
// Scale V rows by colSrcp in place: Vtb[bh][d][k] *= colSrcp[bh][k]  (bf16)
// ---------------------------------------------------------------------------
__launch_bounds__(256) __global__
void scale_v(unsigned short* __restrict__ Vtb, const float* __restrict__ colSrcp) {
    const size_t t8 = ((size_t)blockIdx.x * 256 + threadIdx.x) * 8;
    const int k = (int)(t8 & (NKEY - 1));
    const int bh = (int)(t8 >> 17);  // / (DHEAD * NKEY)
    const float* cs = colSrcp + ((size_t)bh << 11) + k;
    short8 v = *(const short8*)(Vtb + t8);
    float4 c0 = *(const float4*)cs;
    float4 c1 = *(const float4*)(cs + 4);
    short8 o;
    o[0] = (short)f2b(b2f((unsigned short)v[0]) * c0.x);
    o[1] = (short)f2b(b2f((unsigned short)v[1]) * c0.y);
    o[2] = (short)f2b(b2f((unsigned short)v[2]) * c0.z);
    o[3] = (short)f2b(b2f((unsigned short)v[3]) * c0.w);
    o[4] = (short)f2b(b2f((unsigned short)v[4]) * c1.x);
    o[5] = (short)f2b(b2f((unsigned short)v[5]) * c1.y);
    o[6] = (short)f2b(b2f((unsigned short)v[6]) * c1.z);
    o[7] = (short)f2b(b2f((unsigned short)v[7]) * c1.w);
    *(short8*)(Vtb + t8) = o;
}

// ---------------------------------------------------------------------------
// Pass 2: F = exp2(S'); O = F @ (cV); rq = F @ c (ones-trick MFMA);
// attnb = bf16(O / (1e-12 + rq)). Swapped QK. NOW 128-key tiles (one barrier
// per 128 keys, was per 64), cvt_pk E-pack, exp2.
// K tile [128][64]; V as 2 granules of [64 d][64 k]. Same swizzle as before.
// Grid: (NQ/128, BH) = 512 blocks, 512 thr / 8 waves; LDS 74 KB.
// ---------------------------------------------------------------------------
__launch_bounds__(512) __global__
void attn_pass2(const unsigned short* __restrict__ Qh,
                const unsigned short* __restrict__ Kh,
                const unsigned short* __restrict__ Vt,   // pre-scaled by c
                const unsigned short* __restrict__ cb,   // bf16 colSrcp
                unsigned short* __restrict__ attnb) {
    __shared__ unsigned short Kt[2][128 * 64];     // 32 KB
    __shared__ unsigned short Vg[2][2][64 * 64];   // 32 KB (2 k-granules)
    __shared__ unsigned short Elds[8][16][40];     // 10 KB, wave-private
    const int tid = threadIdx.x;
    const int w = tid >> 6, lane = tid & 63;
    const int l16 = lane & 15, q4 = lane >> 4;
    const int bh = blockIdx.y;
    const int b = bh >> 3, h = bh & 7;
    const int q0w = blockIdx.x * 128 + w * 16;

    short8 aq0, aq1;
    {
        const unsigned short* Qrow = Qh + ((size_t)bh * NQ + q0w + l16) * DHEAD;
        aq0 = *(const short8*)(Qrow + q4 * 8);
        aq1 = *(const short8*)(Qrow + 32 + q4 * 8);
    }
    const unsigned short* Kb = Kh + (size_t)bh * NKEY * DHEAD;
    const unsigned short* Vb = Vt + (size_t)bh * DHEAD * NKEY;
    const unsigned short* cbb = cb + (size_t)bh * NKEY;
    char* Ew = (char*)&Elds[w][0][0];

    const int srow = tid >> 3;            // 0..63
    const int skoff = (tid & 7) * 8;
    const int ssw = ((tid & 7) * 16) ^ ((srow & 7) << 4);
    const int rsw = (l16 & 7) << 4;

    f32x4 z = {0.f, 0.f, 0.f, 0.f};
    f32x4 o[4];
    #pragma unroll
    for (int t = 0; t < 4; ++t) o[t] = z;
    f32x4 o5 = z;  // rq accumulator

    // prologue: tile0 (k 0..127) -> buf0; tile1 into regs
    short8 kst[2], vst[2];
    kst[0] = *(const short8*)(Kb + (size_t)srow * DHEAD + skoff);
    kst[1] = *(const short8*)(Kb + (size_t)(64 + srow) * DHEAD + skoff);
    vst[0] = *(const short8*)(Vb + (size_t)srow * NKEY + skoff);
    vst[1] = *(const short8*)(Vb + (size_t)srow * NKEY + 64 + skoff);
    {
        char* K0 = (char*)&Kt[0][0];
        char* V0 = (char*)&Vg[0][0][0];
        *(short8*)(K0 + srow * 128 + ssw) = kst[0];
        *(short8*)(K0 + (64 + srow) * 128 + ssw) = kst[1];
        *(short8*)(V0 + srow * 128 + ssw) = vst[0];
        *(short8*)(V0 + 8192 + srow * 128 + ssw) = vst[1];
    }
    kst[0] = *(const short8*)(Kb + (size_t)(128 + srow) * DHEAD + skoff);
    kst[1] = *(const short8*)(Kb + (size_t)(192 + srow) * DHEAD + skoff);
    vst[0] = *(const short8*)(Vb + (size_t)srow * NKEY + 128 + skoff);
    vst[1] = *(const short8*)(Vb + (size_t)srow * NKEY + 192 + skoff);
    __syncthreads();

    for (int it = 0; it < 16; ++it) {
        const int kb = it * 128;
        char* KtB = (char*)&Kt[it & 1][0];
        char* VgB = (char*)&Vg[it & 1][0][0];

        if (it < 15) {  // stage tile it+1; prefetch tile it+2
            char* KtN = (char*)&Kt[(it & 1) ^ 1][0];
            char* VgN = (char*)&Vg[(it & 1) ^ 1][0][0];
            *(short8*)(KtN + srow * 128 + ssw) = kst[0];
            *(short8*)(KtN + (64 + srow) * 128 + ssw) = kst[1];
            *(short8*)(VgN + srow * 128 + ssw) = vst[0];
            *(short8*)(VgN + 8192 + srow * 128 + ssw) = vst[1];
            if (it < 14) {
                const int kn = kb + 256;
                kst[0] = *(const short8*)(Kb + (size_t)(kn + srow) * DHEAD + skoff);
                kst[1] = *(const short8*)(Kb + (size_t)(kn + 64 + srow) * DHEAD + skoff);
                vst[0] = *(const short8*)(Vb + (size_t)srow * NKEY + kn + skoff);
                vst[1] = *(const short8*)(Vb + (size_t)srow * NKEY + kn + 64 + skoff);
            }
        }

        #pragma unroll
        for (int sub = 0; sub < 4; ++sub) {
            // K fragments (A-operand rows = k)
            short8 bk[2][2];
            #pragma unroll
            for (int jt = 0; jt < 2; ++jt) {
                const int row = sub * 32 + jt * 16 + l16;
                bk[jt][0] = *(const short8*)(KtB + row * 128 + ((q4 * 16) ^ rsw));
                bk[jt][1] = *(const short8*)(KtB + row * 128 + ((64 + q4 * 16) ^ rsw));
            }
            // V fragments (B-operand cols = d); granule = sub>>1
            short8 bv[4];
            #pragma unroll
            for (int t = 0; t < 4; ++t) {
                const int row = t * 16 + l16;
                bv[t] = *(const short8*)(VgB + (sub >> 1) * 8192 + row * 128 +
                                         (((sub & 1) * 64 + q4 * 16) ^ rsw));
            }
            // broadcast c fragment
            short8 bv5 = *(const short8*)(cbb + kb + sub * 32 + q4 * 8);

            // Swapped QK: thread holds S'[q=l16][k = kb + sub*32 + jt*16 + q4*4 + r]
            #pragma unroll
            for (int jt = 0; jt < 2; ++jt) {
                __builtin_amdgcn_s_setprio(1);
                f32x4 st = MFMA16(bk[jt][0], aq0, z);
                st = MFMA16(bk[jt][1], aq1, st);
                __builtin_amdgcn_s_setprio(0);
                uint2 p;
                p.x = pkbf(ex2(st[0]), ex2(st[1]));
                p.y = pkbf(ex2(st[2]), ex2(st[3]));
                *(uint2*)(Ew + l16 * 80 + jt * 32 + q4 * 8) = p;
            }
            short8 ea = *(const short8*)(Ew + l16 * 80 + q4 * 16);
            __builtin_amdgcn_s_setprio(1);
            #pragma unroll
            for (int t = 0; t < 4; ++t)
                o[t] = MFMA16(ea, bv[t], o[t]);
            o5 = MFMA16(ea, bv5, o5);
            __builtin_amdgcn_s_setprio(0);
        }
        __syncthreads();
    }

    float rr[4];
    #pragma unroll
    for (int r = 0; r < 4; ++r) rr[r] = 1.0f / (1e-12f + o5[r]);
    #pragma unroll
    for (int t = 0; t < 4; ++t)
        #pragma unroll
        for (int r = 0; r < 4; ++r) {
            const int q = q0w + q4 * 4 + r;
            attnb[((size_t)b * NQ + q) * DMODEL + h * DHEAD + t * 16 + l16] =
                f2b(o[t][r] * rr[r]);
        }
}

// ---------------------------------------------------------------------------
extern "C" void kernel_launch(void* const* d_in, const int* in_sizes, int n_in,
                              void* d_out, int out_size, void* d_ws, size_t ws_size,
                              hipStream_t stream) {
    const float* init_query = (const float*)d_in[0];
    const float* embedding  = (const float*)d_in[1];
    const float* Wq = (const float*)d_in[2];
    const float* Wk = (const float*)d_in[3];
    const float* Wv = (const float*)d_in[4];
    const float* W0 = (const float*)d_in[5];
    const float* b0 = (const float*)d_in[6];
    const float* W1 = (const float*)d_in[7];
    const float* b1 = (const float*)d_in[8];
    float* out = (float*)d_out;

    const size_t ACT = (size_t)BATCH * NQ * DMODEL;   // 4M elements
    const size_t WEL = (size_t)DMODEL * DMODEL;       // 256K elements

    unsigned short* Xq   = (unsigned short*)d_ws;          // bf16 init_query
    unsigned short* Xe   = Xq + ACT;                       // bf16 embedding
    unsigned short* Wt   = Xe + ACT;                       // 5 transposed weights
    unsigned short* Qh   = Wt + 5 * WEL;                   // [bh][q][d]
    unsigned short* Kh   = Qh + ACT;                       // [bh][k][d]
    unsigned short* Vtb  = Kh + ACT;                       // [bh][d][k]
    unsigned short* attnb= Vtb + ACT;                      // [8192][512]
    unsigned short* ybuf = attnb + ACT;                    // [8192][512]
    float* colSrcp = (float*)(ybuf + ACT);                 // [bh][k] f32

    // cbuf (bf16 colSrcp) aliases ybuf (dead until the W0-GEMM).
    unsigned short* cbuf = ybuf;

    unsigned short* W0t = Wt + 3 * WEL;
    unsigned short* W1t = Wt + 4 * WEL;

    const int M = BATCH * NQ;  // 8192
    dim3 blk(256);
    dim3 blk512(512);
    dim3 gGemm(M / 128, DMODEL / 64);  // 64 x 8

    cast_x<<<dim3(ACT / 1024, 2), blk, 0, stream>>>(init_query, embedding, Xq, Xe);
    trans_w<<<dim3(16, 16, 5), blk, 0, stream>>>(Wq, Wk, Wv, W0, W1, Wt);

    gemm_qkv<<<dim3(M / 128, DMODEL / 64, 3), blk, 0, stream>>>(Xq, Xe, Wt, Qh, Kh, Vtb);

    attn_pass1<<<dim3(NKEY / 128, BH), blk512, 0, stream>>>(Qh, Kh, colSrcp, cbuf);
    scale_v<<<dim3(ACT / 2048), blk, 0, stream>>>(Vtb, colSrcp);
    attn_pass2<<<dim3(NQ / 128, BH), blk512, 0, stream>>>(Qh, Kh, Vtb, cbuf, attnb);

    gemm_bf16<2><<<gGemm, blk, 0, stream>>>(attnb, W0t, ybuf, b0, init_query, M, DMODEL, DMODEL);
    gemm_bf16<3><<<gGemm, blk, 0, stream>>>(ybuf, W1t, out, b1, nullptr, M, DMODEL, DMODEL);
}